// Round 1
// baseline (3402.086 us; speedup 1.0000x reference)
//
#include <hip/hip_runtime.h>
#include <math.h>

// ---------------------------------------------------------------------------
// MambaPredictor forward, fp32 throughout. Correctness-first baseline.
// B=4 L=1024 NF=64 DM=256 DS=16 SCS=8 NL=4 DI=512 DTR=16 DC=4 NFM=6 NH=4
// ---------------------------------------------------------------------------

__device__ __forceinline__ float geluf(float x){ return 0.5f*x*(1.0f + erff(x*0.70710678118654752f)); }
__device__ __forceinline__ float siluf(float x){ return x/(1.0f + expf(-x)); }
__device__ __forceinline__ float softplusf_(float x){ return (x > 20.f) ? x : log1pf(expf(x)); }

// block-wide sum over 256 threads (4 waves of 64)
__device__ __forceinline__ float blk_sum256(float v, volatile float* tmp){
  #pragma unroll
  for (int o = 32; o > 0; o >>= 1) v += __shfl_down(v, o, 64);
  if ((threadIdx.x & 63) == 0) tmp[threadIdx.x >> 6] = v;
  __syncthreads();
  float r = tmp[0] + tmp[1] + tmp[2] + tmp[3];
  __syncthreads();
  return r;
}

// ---------------- initial: h = gelu(LN(x @ in_w^T + in_b)) -----------------
__global__ __launch_bounds__(256) void k_inproj(
    const float* __restrict__ x, const float* __restrict__ w,
    const float* __restrict__ b, const float* __restrict__ g,
    const float* __restrict__ beta, float* __restrict__ h)
{
  __shared__ float xr[64];
  __shared__ float r1[4], r2[4];
  int row = blockIdx.x;
  int tid = threadIdx.x;
  if (tid < 64) xr[tid] = x[row*64 + tid];
  __syncthreads();
  float acc = b[tid];
  const float* wr = w + tid*64;
  #pragma unroll
  for (int k = 0; k < 64; k++) acc += xr[k]*wr[k];
  float s1 = acc, s2 = acc*acc;
  #pragma unroll
  for (int o = 32; o > 0; o >>= 1){ s1 += __shfl_down(s1,o,64); s2 += __shfl_down(s2,o,64); }
  if ((tid & 63) == 0){ r1[tid>>6] = s1; r2[tid>>6] = s2; }
  __syncthreads();
  float S1 = r1[0]+r1[1]+r1[2]+r1[3];
  float S2 = r2[0]+r2[1]+r2[2]+r2[3];
  float m = S1*(1.f/256.f);
  float var = S2*(1.f/256.f) - m*m;
  float xn = (acc - m)*rsqrtf(var + 1e-5f)*g[tid] + beta[tid];
  h[row*256 + tid] = geluf(xn);
}

// ---------------- LayerNorm over 256, gather rows from h -------------------
// src row = b*1024 + src_off + t ; dst row = blockIdx.x (compact)
__global__ __launch_bounds__(256) void k_ln(
    const float* __restrict__ src, const float* __restrict__ g, const float* __restrict__ beta,
    float* __restrict__ dst, int rows_per_b, int src_off)
{
  __shared__ float r1[4], r2[4];
  int r = blockIdx.x, tid = threadIdx.x;
  int b = r / rows_per_b, t = r % rows_per_b;
  float v = src[(b*1024 + src_off + t)*256 + tid];
  float s1 = v, s2 = v*v;
  #pragma unroll
  for (int o = 32; o > 0; o >>= 1){ s1 += __shfl_down(s1,o,64); s2 += __shfl_down(s2,o,64); }
  if ((tid & 63) == 0){ r1[tid>>6] = s1; r2[tid>>6] = s2; }
  __syncthreads();
  float S1 = r1[0]+r1[1]+r1[2]+r1[3];
  float S2 = r2[0]+r2[1]+r2[2]+r2[3];
  float m = S1*(1.f/256.f);
  float var = S2*(1.f/256.f) - m*m;
  dst[r*256 + tid] = (v - m)*rsqrtf(var + 1e-5f)*g[tid] + beta[tid];
}

// ---------------- generic tiled GEMM: C = A(M,K) @ W(N,K)^T ----------------
// MODE 0: store C[r*N+c]
// MODE 1: C[r*N+c] = resid[map(r)*256+c] + v        (N==256)
// MODE 2: atomicAdd(pool_out[b*768+pool_off+c], (resid+v)*pool_scale) (N==256)
template<int MODE>
__global__ __launch_bounds__(256) void k_gemm(
    const float* __restrict__ A, const float* __restrict__ W,
    float* __restrict__ C,
    const float* __restrict__ resid, int rows_per_b, int res_off,
    float* __restrict__ pool_out, int pool_off, float pool_scale,
    int M, int N, int K)
{
  __shared__ float As[16][68];
  __shared__ float Bs[16][68];
  int n0 = blockIdx.x * 64, m0 = blockIdx.y * 64;
  int tid = threadIdx.x;
  int tx = tid & 15, ty = tid >> 4;
  float acc[4][4] = {};
  for (int k0 = 0; k0 < K; k0 += 16){
    {
      int r = tid >> 2, k4 = (tid & 3) * 4;
      int gr = m0 + r;
      float4 av = (gr < M) ? *(const float4*)(A + gr*K + k0 + k4) : make_float4(0.f,0.f,0.f,0.f);
      As[k4+0][r] = av.x; As[k4+1][r] = av.y; As[k4+2][r] = av.z; As[k4+3][r] = av.w;
      int gn = n0 + r;
      float4 bv = (gn < N) ? *(const float4*)(W + gn*K + k0 + k4) : make_float4(0.f,0.f,0.f,0.f);
      Bs[k4+0][r] = bv.x; Bs[k4+1][r] = bv.y; Bs[k4+2][r] = bv.z; Bs[k4+3][r] = bv.w;
    }
    __syncthreads();
    #pragma unroll
    for (int kk = 0; kk < 16; kk++){
      float4 a = *(const float4*)&As[kk][ty*4];
      float4 bb = *(const float4*)&Bs[kk][tx*4];
      acc[0][0] += a.x*bb.x; acc[0][1] += a.x*bb.y; acc[0][2] += a.x*bb.z; acc[0][3] += a.x*bb.w;
      acc[1][0] += a.y*bb.x; acc[1][1] += a.y*bb.y; acc[1][2] += a.y*bb.z; acc[1][3] += a.y*bb.w;
      acc[2][0] += a.z*bb.x; acc[2][1] += a.z*bb.y; acc[2][2] += a.z*bb.z; acc[2][3] += a.z*bb.w;
      acc[3][0] += a.w*bb.x; acc[3][1] += a.w*bb.y; acc[3][2] += a.w*bb.z; acc[3][3] += a.w*bb.w;
    }
    __syncthreads();
  }
  #pragma unroll
  for (int i = 0; i < 4; i++){
    int r = m0 + ty*4 + i;
    if (r >= M) continue;
    int b = r / rows_per_b, t = r % rows_per_b;
    #pragma unroll
    for (int j = 0; j < 4; j++){
      int c = n0 + tx*4 + j;
      if (c >= N) continue;
      float v = acc[i][j];
      if (MODE == 0){
        C[r*N + c] = v;
      } else {
        float rv = resid[(b*1024 + res_off + t)*256 + c] + v;
        if (MODE == 1) C[r*N + c] = rv;
        else atomicAdd(&pool_out[b*768 + pool_off + c], rv*pool_scale);
      }
    }
  }
}

// ---------------- depthwise causal conv (DC=4) + SiLU ----------------------
// u lives in uz columns [0,512), row stride 1024
__global__ __launch_bounds__(256) void k_conv(
    const float* __restrict__ uz, const float* __restrict__ cw, const float* __restrict__ cb,
    float* __restrict__ uc, int Lseq)
{
  int row = blockIdx.x;
  int t = row % Lseq;
  int tid = threadIdx.x;
  for (int d = tid; d < 512; d += 256){
    float acc = cb[d];
    const float* w = cw + d*4;
    #pragma unroll
    for (int k = 0; k < 4; k++){
      int ts = t - 3 + k;
      if (ts >= 0) acc += uz[(row - (3-k))*1024 + d]*w[k];
    }
    uc[row*512 + d] = acc*siluf(1.f)*0.f + acc/(1.f + expf(-acc))*1.f; // silu
  }
}

// ---------------- dt = softplus(xd[:16] @ dtw^T + dtb) ---------------------
__global__ __launch_bounds__(256) void k_dt(
    const float* __restrict__ xd, const float* __restrict__ dtw, const float* __restrict__ dtb,
    float* __restrict__ dt, int xdld)
{
  __shared__ float sx[16];
  int row = blockIdx.x, tid = threadIdx.x;
  if (tid < 16) sx[tid] = xd[row*xdld + tid];
  __syncthreads();
  for (int d = tid; d < 512; d += 256){
    float acc = dtb[d];
    const float* w = dtw + d*16;
    #pragma unroll
    for (int j = 0; j < 16; j++) acc += sx[j]*w[j];
    dt[row*512 + d] = softplusf_(acc);
  }
}

// ---------------- selective scan + gate -------------------------------------
// block = 16 d-channels x ds state dims; grid = (32 dblk, B)
__global__ __launch_bounds__(256) void k_scan(
    const float* __restrict__ dt, const float* __restrict__ uc, const float* __restrict__ uz,
    const float* __restrict__ xd, const float* __restrict__ Alog, const float* __restrict__ Dp,
    float* __restrict__ yg, int Lseq, int ds, int xdld)
{
  const int TC = 32;
  __shared__ float sdt[TC][16], suc[TC][16], sz[TC][16], sy[TC][16];
  __shared__ float sB[TC][16], sC[TC][16];
  int dblk = blockIdx.x, b = blockIdx.y;
  int nth = blockDim.x;
  int tid = threadIdx.x;
  int di = tid / ds, n = tid % ds;
  int d = dblk*16 + di;
  float A = -expf(Alog[d*ds + n]);
  float Dv = Dp[d];
  float h = 0.f;
  for (int t0 = 0; t0 < Lseq; t0 += TC){
    int tcnt = min(TC, Lseq - t0);
    for (int e = tid; e < tcnt*16; e += nth){
      int tt = e >> 4, dd = e & 15;
      int row = b*Lseq + t0 + tt;
      sdt[tt][dd] = dt[row*512 + dblk*16 + dd];
      suc[tt][dd] = uc[row*512 + dblk*16 + dd];
      sz[tt][dd]  = uz[row*1024 + 512 + dblk*16 + dd];
    }
    for (int e = tid; e < tcnt*ds; e += nth){
      int tt = e / ds, nn = e % ds;
      int row = b*Lseq + t0 + tt;
      sB[tt][nn] = xd[row*xdld + 16 + nn];
      sC[tt][nn] = xd[row*xdld + 16 + ds + nn];
    }
    __syncthreads();
    for (int tt = 0; tt < tcnt; tt++){
      float dtv = sdt[tt][di];
      float uv  = suc[tt][di];
      float da  = __expf(dtv*A);
      h = da*h + dtv*sB[tt][n]*uv;
      float pv = h*sC[tt][n];
      for (int mask = ds >> 1; mask; mask >>= 1) pv += __shfl_xor(pv, mask, 64);
      if (n == 0){
        float y = pv + uv*Dv;
        float zv = sz[tt][di];
        sy[tt][di] = y*(zv/(1.f + expf(-zv)));
      }
    }
    __syncthreads();
    for (int e = tid; e < tcnt*16; e += nth){
      int tt = e >> 4, dd = e & 15;
      int row = b*Lseq + t0 + tt;
      yg[row*512 + dblk*16 + dd] = sy[tt][dd];
    }
    __syncthreads();
  }
}

__global__ void k_zero(float* p, int n){
  int i = blockIdx.x*256 + threadIdx.x;
  if (i < n) p[i] = 0.f;
}

// ---------------- tail: MHA x2 + FFN + heads (one block per batch) ----------
__device__ void mha_dev(const float* in, float* qkv, float* att, float* ov, float* mo,
                        const float* wqkv, const float* bqkv,
                        const float* wout, const float* bout)
{
  int tid = threadIdx.x;
  for (int e = tid; e < 2304; e += 256){
    int p = e / 768, j = e % 768;
    float acc = bqkv[j];
    const float* wr = wqkv + j*256;
    for (int k = 0; k < 256; k++) acc += in[p*256 + k]*wr[k];
    qkv[p*768 + j] = acc;
  }
  __syncthreads();
  if (tid < 36){
    int hh = tid/9, r = (tid%9)/3, c = tid%3;
    float s = 0.f;
    for (int k = 0; k < 64; k++) s += qkv[r*768 + hh*64 + k]*qkv[c*768 + 256 + hh*64 + k];
    att[hh*9 + r*3 + c] = s*0.125f;
  }
  __syncthreads();
  if (tid < 12){
    int hh = tid/3, r = tid%3;
    float a0 = att[hh*9+r*3+0], a1 = att[hh*9+r*3+1], a2 = att[hh*9+r*3+2];
    float m = fmaxf(a0, fmaxf(a1, a2));
    float e0 = expf(a0-m), e1 = expf(a1-m), e2 = expf(a2-m);
    float s = e0+e1+e2;
    att[hh*9+r*3+0] = e0/s; att[hh*9+r*3+1] = e1/s; att[hh*9+r*3+2] = e2/s;
  }
  __syncthreads();
  for (int e = tid; e < 768; e += 256){
    int p = e >> 8, i = e & 255, hh = i >> 6;
    ov[p*256 + i] = att[hh*9+p*3+0]*qkv[0*768+512+i]
                  + att[hh*9+p*3+1]*qkv[1*768+512+i]
                  + att[hh*9+p*3+2]*qkv[2*768+512+i];
  }
  __syncthreads();
  for (int e = tid; e < 768; e += 256){
    int p = e >> 8, i = e & 255;
    float acc = bout[i];
    const float* wr = wout + i*256;
    for (int k = 0; k < 256; k++) acc += ov[p*256 + k]*wr[k];
    mo[p*256 + i] = acc;
  }
  __syncthreads();
}

__device__ void ln3_dev(const float* in, float* outp, const float* g, const float* bb, volatile float* tmp)
{
  int tid = threadIdx.x;
  for (int p = 0; p < 3; p++){
    float v = in[p*256 + tid];
    float s1 = blk_sum256(v, tmp);
    float s2 = blk_sum256(v*v, tmp);
    float m = s1*(1.f/256.f);
    float var = s2*(1.f/256.f) - m*m;
    outp[p*256 + tid] = (v - m)*rsqrtf(var + 1e-5f)*g[tid] + bb[tid];
  }
  __syncthreads();
}

__global__ __launch_bounds__(256) void k_tail(
    const float* __restrict__ stack,
    const float* fqw, const float* fqb, const float* fow, const float* fob,
    const float* msw, const float* msb,
    const float* l1g, const float* l1b, const float* l2g, const float* l2b,
    const float* sqw, const float* sqb, const float* sow, const float* sob,
    const float* f1w, const float* f1b, const float* f2w, const float* f2b,
    const float* e1w, const float* e1b, const float* e2w, const float* e2b,
    const float* t1w, const float* t1b, const float* t2w, const float* t2b,
    const float* ew, const float* eb,
    float* __restrict__ out)
{
  __shared__ float st[768], lnr[768], qkv[2304], att[36], ov[768], mo[768];
  __shared__ float s2buf[768], hid[3072], fusedv[256], finalv[256];
  __shared__ float red[4];
  __shared__ float sv[32];
  __shared__ float evh[256], tth[128];
  int b = blockIdx.x, tid = threadIdx.x;

  for (int e = tid; e < 768; e += 256) st[e] = stack[b*768 + e];
  __syncthreads();

  // fused path: MHA on raw stack, then reshape @ ms_out
  mha_dev(st, qkv, att, ov, mo, fqw, fqb, fow, fob);
  {
    float acc = msb[tid];
    const float* wr = msw + tid*768;
    for (int k = 0; k < 768; k++) acc += mo[k]*wr[k];
    fusedv[tid] = acc;
  }
  __syncthreads();

  // sa path: s2 = stack + MHA(LN1(stack))
  ln3_dev(st, lnr, l1g, l1b, red);
  mha_dev(lnr, qkv, att, ov, mo, sqw, sqb, sow, sob);
  for (int e = tid; e < 768; e += 256) s2buf[e] = st[e] + mo[e];
  __syncthreads();

  // FFN: s2 += ff2(gelu(ff1(LN2(s2))))
  ln3_dev(s2buf, lnr, l2g, l2b, red);
  for (int e = tid; e < 3072; e += 256){
    int p = e >> 10, j = e & 1023;
    float acc = f1b[j];
    const float* wr = f1w + j*256;
    for (int k = 0; k < 256; k++) acc += lnr[p*256 + k]*wr[k];
    hid[p*1024 + j] = geluf(acc);
  }
  __syncthreads();
  for (int e = tid; e < 768; e += 256){
    int p = e >> 8, i = e & 255;
    float acc = f2b[i];
    const float* wr = f2w + i*1024;
    for (int k = 0; k < 1024; k++) acc += hid[p*1024 + k]*wr[k];
    s2buf[e] += acc;
  }
  __syncthreads();

  finalv[tid] = fusedv[tid] + (s2buf[tid] + s2buf[256+tid] + s2buf[512+tid])*(1.f/3.f);
  __syncthreads();

  // heads
  {
    float acc = e1b[tid];
    const float* wr = e1w + tid*256;
    for (int k = 0; k < 256; k++) acc += finalv[k]*wr[k];
    evh[tid] = geluf(acc);
  }
  __syncthreads();
  if (tid < 7){
    float acc = e2b[tid];
    const float* wr = e2w + tid*256;
    for (int k = 0; k < 256; k++) acc += evh[k]*wr[k];
    sv[tid] = softplusf_(acc);
  }
  __syncthreads();
  if (tid == 0){
    float s = 0.f;
    for (int j = 0; j < 7; j++) s += sv[j] + 1.f;
    sv[8] = s;
  }
  if (tid < 128){
    float acc = t1b[tid];
    const float* wr = t1w + tid*256;
    for (int k = 0; k < 256; k++) acc += finalv[k]*wr[k];
    tth[tid] = geluf(acc);
  }
  __syncthreads();
  if (tid < 12){
    float acc = t2b[tid];
    const float* wr = t2w + tid*128;
    for (int k = 0; k < 128; k++) acc += tth[k]*wr[k];
    sv[16 + tid] = acc;
  }
  __syncthreads();

  float* ob = out + b*162;
  if (tid < 7){
    float ev = sv[tid], al = ev + 1.f;
    ob[tid] = al / sv[8];
    ob[7 + tid] = ev;
    ob[14 + tid] = al;
  }
  if (tid == 0) ob[21] = 7.f / sv[8];
  if (tid < 6){
    ob[22 + tid] = softplusf_(sv[16 + tid]);
    ob[28 + tid] = expf(0.5f*sv[22 + tid]);
  }
  if (tid < 128){
    float acc = eb[tid];
    const float* wr = ew + tid*256;
    for (int k = 0; k < 256; k++) acc += finalv[k]*wr[k];
    ob[34 + tid] = acc;
  }
}

// ---------------------------------------------------------------------------
extern "C" void kernel_launch(void* const* d_in, const int* in_sizes, int n_in,
                              void* d_out, int out_size, void* d_ws, size_t ws_size,
                              hipStream_t stream)
{
  const float* x         = (const float*)d_in[0];
  const float* in_w      = (const float*)d_in[1];
  const float* in_b      = (const float*)d_in[2];
  const float* in_ln_g   = (const float*)d_in[3];
  const float* in_ln_b   = (const float*)d_in[4];
  const float* mb_ln_g   = (const float*)d_in[5];
  const float* mb_ln_b   = (const float*)d_in[6];
  const float* mb_in_w   = (const float*)d_in[7];
  const float* mb_conv_w = (const float*)d_in[8];
  const float* mb_conv_b = (const float*)d_in[9];
  const float* mb_xp_w   = (const float*)d_in[10];
  const float* mb_dt_w   = (const float*)d_in[11];
  const float* mb_dt_b   = (const float*)d_in[12];
  const float* mb_Alog   = (const float*)d_in[13];
  const float* mb_D      = (const float*)d_in[14];
  const float* mb_out_w  = (const float*)d_in[15];
  const float* sc_ln_g   = (const float*)d_in[16];
  const float* sc_ln_b   = (const float*)d_in[17];
  const float* sc_in_w   = (const float*)d_in[18];
  const float* sc_conv_w = (const float*)d_in[19];
  const float* sc_conv_b = (const float*)d_in[20];
  const float* sc_xp_w   = (const float*)d_in[21];
  const float* sc_dt_w   = (const float*)d_in[22];
  const float* sc_dt_b   = (const float*)d_in[23];
  const float* sc_Alog   = (const float*)d_in[24];
  const float* sc_D      = (const float*)d_in[25];
  const float* sc_out_w  = (const float*)d_in[26];
  const float* fus_qkv_w = (const float*)d_in[27];
  const float* fus_qkv_b = (const float*)d_in[28];
  const float* fus_out_w = (const float*)d_in[29];
  const float* fus_out_b = (const float*)d_in[30];
  const float* ms_out_w  = (const float*)d_in[31];
  const float* ms_out_b  = (const float*)d_in[32];
  const float* sa_ln1_g  = (const float*)d_in[33];
  const float* sa_ln1_b  = (const float*)d_in[34];
  const float* sa_ln2_g  = (const float*)d_in[35];
  const float* sa_ln2_b  = (const float*)d_in[36];
  const float* sa_qkv_w  = (const float*)d_in[37];
  const float* sa_qkv_b  = (const float*)d_in[38];
  const float* sa_out_w  = (const float*)d_in[39];
  const float* sa_out_b  = (const float*)d_in[40];
  const float* sa_ff1_w  = (const float*)d_in[41];
  const float* sa_ff1_b  = (const float*)d_in[42];
  const float* sa_ff2_w  = (const float*)d_in[43];
  const float* sa_ff2_b  = (const float*)d_in[44];
  const float* ev1_w     = (const float*)d_in[45];
  const float* ev1_b     = (const float*)d_in[46];
  const float* ev2_w     = (const float*)d_in[47];
  const float* ev2_b     = (const float*)d_in[48];
  const float* ttf1_w    = (const float*)d_in[49];
  const float* ttf1_b    = (const float*)d_in[50];
  const float* ttf2_w    = (const float*)d_in[51];
  const float* ttf2_b    = (const float*)d_in[52];
  const float* emb_w     = (const float*)d_in[53];
  const float* emb_b     = (const float*)d_in[54];

  float* ws = (float*)d_ws;
  float* h     = ws;                   // 4*1024*256   = 1,048,576
  float* xn    = h  + 1048576;         // 1,048,576
  float* uz    = xn + 1048576;         // 4*1024*1024  = 4,194,304
  float* uc    = uz + 4194304;         // 4*1024*512   = 2,097,152
  float* dtb_  = uc + 2097152;         // 2,097,152
  float* xd    = dtb_ + 2097152;       // 4*1024*48    = 196,608
  float* yg    = xd + 196608;          // 2,097,152
  float* stack = yg + 2097152;         // 3,072

  // initial projection + LN + gelu
  k_inproj<<<4096, 256, 0, stream>>>(x, in_w, in_b, in_ln_g, in_ln_b, h);

  // 4 main mamba layers (L=1024, ds=16, xdld=48)
  for (int l = 0; l < 4; l++){
    k_ln<<<4096, 256, 0, stream>>>(h, mb_ln_g + l*256, mb_ln_b + l*256, xn, 1024, 0);
    {
      dim3 g(16, 64);
      k_gemm<0><<<g, 256, 0, stream>>>(xn, mb_in_w + l*262144, uz,
                                       nullptr, 1, 0, nullptr, 0, 0.f, 4096, 1024, 256);
    }
    k_conv<<<4096, 256, 0, stream>>>(uz, mb_conv_w + l*2048, mb_conv_b + l*512, uc, 1024);
    {
      dim3 g(1, 64);
      k_gemm<0><<<g, 256, 0, stream>>>(uc, mb_xp_w + l*24576, xd,
                                       nullptr, 1, 0, nullptr, 0, 0.f, 4096, 48, 512);
    }
    k_dt<<<4096, 256, 0, stream>>>(xd, mb_dt_w + l*8192, mb_dt_b + l*512, dtb_, 48);
    {
      dim3 g(32, 4);
      k_scan<<<g, 256, 0, stream>>>(dtb_, uc, uz, xd, mb_Alog + l*8192, mb_D + l*512,
                                    yg, 1024, 16, 48);
    }
    {
      dim3 g(4, 64);
      k_gemm<1><<<g, 256, 0, stream>>>(yg, mb_out_w + l*131072, h,
                                       h, 1024, 0, nullptr, 0, 0.f, 4096, 256, 512);
    }
  }

  // scale mambas -> pooled stack
  k_zero<<<12, 256, 0, stream>>>(stack, 3072);
  const int scales[3] = {5, 20, 50};
  for (int i = 0; i < 3; i++){
    int s = scales[i];
    int rows = 4*s;
    int mb = (rows + 63)/64;
    k_ln<<<rows, 256, 0, stream>>>(h, sc_ln_g + i*256, sc_ln_b + i*256, xn, s, 1024 - s);
    {
      dim3 g(16, mb);
      k_gemm<0><<<g, 256, 0, stream>>>(xn, sc_in_w + i*262144, uz,
                                       nullptr, 1, 0, nullptr, 0, 0.f, rows, 1024, 256);
    }
    k_conv<<<rows, 256, 0, stream>>>(uz, sc_conv_w + i*2048, sc_conv_b + i*512, uc, s);
    {
      dim3 g(1, mb);
      k_gemm<0><<<g, 256, 0, stream>>>(uc, sc_xp_w + i*16384, xd,
                                       nullptr, 1, 0, nullptr, 0, 0.f, rows, 32, 512);
    }
    k_dt<<<rows, 256, 0, stream>>>(xd, sc_dt_w + i*8192, sc_dt_b + i*512, dtb_, 32);
    {
      dim3 g(32, 4);
      k_scan<<<g, 128, 0, stream>>>(dtb_, uc, uz, xd, sc_Alog + i*4096, sc_D + i*512,
                                    yg, s, 8, 32);
    }
    {
      dim3 g(4, mb);
      k_gemm<2><<<g, 256, 0, stream>>>(yg, sc_out_w + i*131072, nullptr,
                                       h, s, 1024 - s, stack, i*256, 1.f/(float)s,
                                       rows, 256, 512);
    }
  }

  // tail
  k_tail<<<4, 256, 0, stream>>>(stack,
      fus_qkv_w, fus_qkv_b, fus_out_w, fus_out_b,
      ms_out_w, ms_out_b,
      sa_ln1_g, sa_ln1_b, sa_ln2_g, sa_ln2_b,
      sa_qkv_w, sa_qkv_b, sa_out_w, sa_out_b,
      sa_ff1_w, sa_ff1_b, sa_ff2_w, sa_ff2_b,
      ev1_w, ev1_b, ev2_w, ev2_b,
      ttf1_w, ttf1_b, ttf2_w, ttf2_b,
      emb_w, emb_b,
      (float*)d_out);
}

// Round 2
// 2346.705 us; speedup vs baseline: 1.4497x; 1.4497x over previous
//
#include <hip/hip_runtime.h>
#include <math.h>

// ---------------------------------------------------------------------------
// MambaPredictor forward, fp32. R1: latency-optimized selective scan.
// B=4 L=1024 NF=64 DM=256 DS=16 SCS=8 NL=4 DI=512 DTR=16 DC=4 NFM=6 NH=4
// ---------------------------------------------------------------------------

__device__ __forceinline__ float geluf(float x){ return 0.5f*x*(1.0f + erff(x*0.70710678118654752f)); }
__device__ __forceinline__ float siluf(float x){ return x/(1.0f + expf(-x)); }
__device__ __forceinline__ float softplusf_(float x){ return (x > 20.f) ? x : log1pf(expf(x)); }

// block-wide sum over 256 threads (4 waves of 64)
__device__ __forceinline__ float blk_sum256(float v, volatile float* tmp){
  #pragma unroll
  for (int o = 32; o > 0; o >>= 1) v += __shfl_down(v, o, 64);
  if ((threadIdx.x & 63) == 0) tmp[threadIdx.x >> 6] = v;
  __syncthreads();
  float r = tmp[0] + tmp[1] + tmp[2] + tmp[3];
  __syncthreads();
  return r;
}

// ---------------- initial: h = gelu(LN(x @ in_w^T + in_b)) -----------------
__global__ __launch_bounds__(256) void k_inproj(
    const float* __restrict__ x, const float* __restrict__ w,
    const float* __restrict__ b, const float* __restrict__ g,
    const float* __restrict__ beta, float* __restrict__ h)
{
  __shared__ float xr[64];
  __shared__ float r1[4], r2[4];
  int row = blockIdx.x;
  int tid = threadIdx.x;
  if (tid < 64) xr[tid] = x[row*64 + tid];
  __syncthreads();
  float acc = b[tid];
  const float* wr = w + tid*64;
  #pragma unroll
  for (int k = 0; k < 64; k++) acc += xr[k]*wr[k];
  float s1 = acc, s2 = acc*acc;
  #pragma unroll
  for (int o = 32; o > 0; o >>= 1){ s1 += __shfl_down(s1,o,64); s2 += __shfl_down(s2,o,64); }
  if ((tid & 63) == 0){ r1[tid>>6] = s1; r2[tid>>6] = s2; }
  __syncthreads();
  float S1 = r1[0]+r1[1]+r1[2]+r1[3];
  float S2 = r2[0]+r2[1]+r2[2]+r2[3];
  float m = S1*(1.f/256.f);
  float var = S2*(1.f/256.f) - m*m;
  float xn = (acc - m)*rsqrtf(var + 1e-5f)*g[tid] + beta[tid];
  h[row*256 + tid] = geluf(xn);
}

// ---------------- LayerNorm over 256, gather rows from h -------------------
__global__ __launch_bounds__(256) void k_ln(
    const float* __restrict__ src, const float* __restrict__ g, const float* __restrict__ beta,
    float* __restrict__ dst, int rows_per_b, int src_off)
{
  __shared__ float r1[4], r2[4];
  int r = blockIdx.x, tid = threadIdx.x;
  int b = r / rows_per_b, t = r % rows_per_b;
  float v = src[(b*1024 + src_off + t)*256 + tid];
  float s1 = v, s2 = v*v;
  #pragma unroll
  for (int o = 32; o > 0; o >>= 1){ s1 += __shfl_down(s1,o,64); s2 += __shfl_down(s2,o,64); }
  if ((tid & 63) == 0){ r1[tid>>6] = s1; r2[tid>>6] = s2; }
  __syncthreads();
  float S1 = r1[0]+r1[1]+r1[2]+r1[3];
  float S2 = r2[0]+r2[1]+r2[2]+r2[3];
  float m = S1*(1.f/256.f);
  float var = S2*(1.f/256.f) - m*m;
  dst[r*256 + tid] = (v - m)*rsqrtf(var + 1e-5f)*g[tid] + beta[tid];
}

// ---------------- generic tiled GEMM: C = A(M,K) @ W(N,K)^T ----------------
template<int MODE>
__global__ __launch_bounds__(256) void k_gemm(
    const float* __restrict__ A, const float* __restrict__ W,
    float* __restrict__ C,
    const float* __restrict__ resid, int rows_per_b, int res_off,
    float* __restrict__ pool_out, int pool_off, float pool_scale,
    int M, int N, int K)
{
  __shared__ float As[16][68];
  __shared__ float Bs[16][68];
  int n0 = blockIdx.x * 64, m0 = blockIdx.y * 64;
  int tid = threadIdx.x;
  int tx = tid & 15, ty = tid >> 4;
  float acc[4][4] = {};
  for (int k0 = 0; k0 < K; k0 += 16){
    {
      int r = tid >> 2, k4 = (tid & 3) * 4;
      int gr = m0 + r;
      float4 av = (gr < M) ? *(const float4*)(A + gr*K + k0 + k4) : make_float4(0.f,0.f,0.f,0.f);
      As[k4+0][r] = av.x; As[k4+1][r] = av.y; As[k4+2][r] = av.z; As[k4+3][r] = av.w;
      int gn = n0 + r;
      float4 bv = (gn < N) ? *(const float4*)(W + gn*K + k0 + k4) : make_float4(0.f,0.f,0.f,0.f);
      Bs[k4+0][r] = bv.x; Bs[k4+1][r] = bv.y; Bs[k4+2][r] = bv.z; Bs[k4+3][r] = bv.w;
    }
    __syncthreads();
    #pragma unroll
    for (int kk = 0; kk < 16; kk++){
      float4 a = *(const float4*)&As[kk][ty*4];
      float4 bb = *(const float4*)&Bs[kk][tx*4];
      acc[0][0] += a.x*bb.x; acc[0][1] += a.x*bb.y; acc[0][2] += a.x*bb.z; acc[0][3] += a.x*bb.w;
      acc[1][0] += a.y*bb.x; acc[1][1] += a.y*bb.y; acc[1][2] += a.y*bb.z; acc[1][3] += a.y*bb.w;
      acc[2][0] += a.z*bb.x; acc[2][1] += a.z*bb.y; acc[2][2] += a.z*bb.z; acc[2][3] += a.z*bb.w;
      acc[3][0] += a.w*bb.x; acc[3][1] += a.w*bb.y; acc[3][2] += a.w*bb.z; acc[3][3] += a.w*bb.w;
    }
    __syncthreads();
  }
  #pragma unroll
  for (int i = 0; i < 4; i++){
    int r = m0 + ty*4 + i;
    if (r >= M) continue;
    int b = r / rows_per_b, t = r % rows_per_b;
    #pragma unroll
    for (int j = 0; j < 4; j++){
      int c = n0 + tx*4 + j;
      if (c >= N) continue;
      float v = acc[i][j];
      if (MODE == 0){
        C[r*N + c] = v;
      } else {
        float rv = resid[(b*1024 + res_off + t)*256 + c] + v;
        if (MODE == 1) C[r*N + c] = rv;
        else atomicAdd(&pool_out[b*768 + pool_off + c], rv*pool_scale);
      }
    }
  }
}

// ---------------- depthwise causal conv (DC=4) + SiLU ----------------------
__global__ __launch_bounds__(256) void k_conv(
    const float* __restrict__ uz, const float* __restrict__ cw, const float* __restrict__ cb,
    float* __restrict__ uc, int Lseq)
{
  int row = blockIdx.x;
  int t = row % Lseq;
  int tid = threadIdx.x;
  for (int d = tid; d < 512; d += 256){
    float acc = cb[d];
    const float* w = cw + d*4;
    #pragma unroll
    for (int k = 0; k < 4; k++){
      int ts = t - 3 + k;
      if (ts >= 0) acc += uz[(row - (3-k))*1024 + d]*w[k];
    }
    uc[row*512 + d] = acc/(1.f + expf(-acc));
  }
}

// ---------------- dt = softplus(xd[:16] @ dtw^T + dtb) ---------------------
__global__ __launch_bounds__(256) void k_dt(
    const float* __restrict__ xd, const float* __restrict__ dtw, const float* __restrict__ dtb,
    float* __restrict__ dt, int xdld)
{
  __shared__ float sx[16];
  int row = blockIdx.x, tid = threadIdx.x;
  if (tid < 16) sx[tid] = xd[row*xdld + tid];
  __syncthreads();
  for (int d = tid; d < 512; d += 256){
    float acc = dtb[d];
    const float* w = dtw + d*16;
    #pragma unroll
    for (int j = 0; j < 16; j++) acc += sx[j]*w[j];
    dt[row*512 + d] = softplusf_(acc);
  }
}

// ---------------- selective scan + gate (R1: off-chain exp & reduce) --------
// block = 16 d-channels x DS state dims; grid = (32 dblk, B)
// Phases per 32-step chunk:
//   P0 vectorized loads -> LDS; P1 precompute da/bu (independent, pipelined);
//   P2 pure fma chain (the only true serialization); P3 batched shfl reduces.
template<int DS>
__global__ __launch_bounds__(256) void k_scan2(
    const float* __restrict__ dt, const float* __restrict__ uc, const float* __restrict__ uz,
    const float* __restrict__ xd, const float* __restrict__ Alog, const float* __restrict__ Dp,
    float* __restrict__ yg, int Lseq, int xdld)
{
  const int TC = 32;
  const int QBC = (2*DS)/4;          // float4 per row of [B|C]
  __shared__ float sdt[TC][16], suc[TC][16], sz[TC][16], sy[TC][16];
  __shared__ float sBC[TC][2*DS];
  int dblk = blockIdx.x, b = blockIdx.y;
  int nth = blockDim.x;
  int tid = threadIdx.x;
  int di = tid / DS, n = tid % DS;
  int d = dblk*16 + di;
  float A = -__expf(Alog[d*DS + n]);
  float Dv = Dp[d];
  float h = 0.f;
  for (int t0 = 0; t0 < Lseq; t0 += TC){
    int tcnt = min(TC, Lseq - t0);
    for (int e = tid; e < tcnt*4; e += nth){
      int tt = e >> 2, q = e & 3;
      long row = (long)(b*Lseq + t0 + tt);
      *(float4*)&sdt[tt][q*4] = *(const float4*)(dt + row*512 + dblk*16 + q*4);
      *(float4*)&suc[tt][q*4] = *(const float4*)(uc + row*512 + dblk*16 + q*4);
      *(float4*)&sz[tt][q*4]  = *(const float4*)(uz + row*1024 + 512 + dblk*16 + q*4);
    }
    for (int e = tid; e < tcnt*QBC; e += nth){
      int tt = e / QBC, q = e % QBC;
      long row = (long)(b*Lseq + t0 + tt);
      *(float4*)&sBC[tt][q*4] = *(const float4*)(xd + row*xdld + 16 + q*4);
    }
    __syncthreads();
    float da[TC], bu[TC];
    #pragma unroll
    for (int tt = 0; tt < TC; tt++){
      float dtv = sdt[tt][di];
      da[tt] = __expf(dtv*A);
      bu[tt] = dtv*suc[tt][di]*sBC[tt][n];
    }
    #pragma unroll
    for (int tt = 0; tt < TC; tt++){
      if (tt < tcnt){
        h = fmaf(da[tt], h, bu[tt]);
        bu[tt] = h*sBC[tt][DS+n];       // pv, off the dependent chain
      }
    }
    #pragma unroll
    for (int tt = 0; tt < TC; tt++){
      float pv = bu[tt];
      #pragma unroll
      for (int m = DS>>1; m; m >>= 1) pv += __shfl_xor(pv, m, 64);
      if (n == 0 && tt < tcnt){
        float y = pv + suc[tt][di]*Dv;
        float zv = sz[tt][di];
        sy[tt][di] = y*(zv/(1.f + __expf(-zv)));
      }
    }
    __syncthreads();
    for (int e = tid; e < tcnt*4; e += nth){
      int tt = e >> 2, q = e & 3;
      long row = (long)(b*Lseq + t0 + tt);
      *(float4*)(yg + row*512 + dblk*16 + q*4) = *(float4*)&sy[tt][q*4];
    }
    __syncthreads();
  }
}

__global__ void k_zero(float* p, int n){
  int i = blockIdx.x*256 + threadIdx.x;
  if (i < n) p[i] = 0.f;
}

// ---------------- tail: MHA x2 + FFN + heads (one block per batch) ----------
__device__ void mha_dev(const float* in, float* qkv, float* att, float* ov, float* mo,
                        const float* wqkv, const float* bqkv,
                        const float* wout, const float* bout)
{
  int tid = threadIdx.x;
  for (int e = tid; e < 2304; e += 256){
    int p = e / 768, j = e % 768;
    float acc = bqkv[j];
    const float* wr = wqkv + j*256;
    for (int k = 0; k < 256; k++) acc += in[p*256 + k]*wr[k];
    qkv[p*768 + j] = acc;
  }
  __syncthreads();
  if (tid < 36){
    int hh = tid/9, r = (tid%9)/3, c = tid%3;
    float s = 0.f;
    for (int k = 0; k < 64; k++) s += qkv[r*768 + hh*64 + k]*qkv[c*768 + 256 + hh*64 + k];
    att[hh*9 + r*3 + c] = s*0.125f;
  }
  __syncthreads();
  if (tid < 12){
    int hh = tid/3, r = tid%3;
    float a0 = att[hh*9+r*3+0], a1 = att[hh*9+r*3+1], a2 = att[hh*9+r*3+2];
    float m = fmaxf(a0, fmaxf(a1, a2));
    float e0 = expf(a0-m), e1 = expf(a1-m), e2 = expf(a2-m);
    float s = e0+e1+e2;
    att[hh*9+r*3+0] = e0/s; att[hh*9+r*3+1] = e1/s; att[hh*9+r*3+2] = e2/s;
  }
  __syncthreads();
  for (int e = tid; e < 768; e += 256){
    int p = e >> 8, i = e & 255, hh = i >> 6;
    ov[p*256 + i] = att[hh*9+p*3+0]*qkv[0*768+512+i]
                  + att[hh*9+p*3+1]*qkv[1*768+512+i]
                  + att[hh*9+p*3+2]*qkv[2*768+512+i];
  }
  __syncthreads();
  for (int e = tid; e < 768; e += 256){
    int p = e >> 8, i = e & 255;
    float acc = bout[i];
    const float* wr = wout + i*256;
    for (int k = 0; k < 256; k++) acc += ov[p*256 + k]*wr[k];
    mo[p*256 + i] = acc;
  }
  __syncthreads();
}

__device__ void ln3_dev(const float* in, float* outp, const float* g, const float* bb, volatile float* tmp)
{
  int tid = threadIdx.x;
  for (int p = 0; p < 3; p++){
    float v = in[p*256 + tid];
    float s1 = blk_sum256(v, tmp);
    float s2 = blk_sum256(v*v, tmp);
    float m = s1*(1.f/256.f);
    float var = s2*(1.f/256.f) - m*m;
    outp[p*256 + tid] = (v - m)*rsqrtf(var + 1e-5f)*g[tid] + bb[tid];
  }
  __syncthreads();
}

__global__ __launch_bounds__(256) void k_tail(
    const float* __restrict__ stack,
    const float* fqw, const float* fqb, const float* fow, const float* fob,
    const float* msw, const float* msb,
    const float* l1g, const float* l1b, const float* l2g, const float* l2b,
    const float* sqw, const float* sqb, const float* sow, const float* sob,
    const float* f1w, const float* f1b, const float* f2w, const float* f2b,
    const float* e1w, const float* e1b, const float* e2w, const float* e2b,
    const float* t1w, const float* t1b, const float* t2w, const float* t2b,
    const float* ew, const float* eb,
    float* __restrict__ out)
{
  __shared__ float st[768], lnr[768], qkv[2304], att[36], ov[768], mo[768];
  __shared__ float s2buf[768], hid[3072], fusedv[256], finalv[256];
  __shared__ float red[4];
  __shared__ float sv[32];
  __shared__ float evh[256], tth[128];
  int b = blockIdx.x, tid = threadIdx.x;

  for (int e = tid; e < 768; e += 256) st[e] = stack[b*768 + e];
  __syncthreads();

  mha_dev(st, qkv, att, ov, mo, fqw, fqb, fow, fob);
  {
    float acc = msb[tid];
    const float* wr = msw + tid*768;
    for (int k = 0; k < 768; k++) acc += mo[k]*wr[k];
    fusedv[tid] = acc;
  }
  __syncthreads();

  ln3_dev(st, lnr, l1g, l1b, red);
  mha_dev(lnr, qkv, att, ov, mo, sqw, sqb, sow, sob);
  for (int e = tid; e < 768; e += 256) s2buf[e] = st[e] + mo[e];
  __syncthreads();

  ln3_dev(s2buf, lnr, l2g, l2b, red);
  for (int e = tid; e < 3072; e += 256){
    int p = e >> 10, j = e & 1023;
    float acc = f1b[j];
    const float* wr = f1w + j*256;
    for (int k = 0; k < 256; k++) acc += lnr[p*256 + k]*wr[k];
    hid[p*1024 + j] = geluf(acc);
  }
  __syncthreads();
  for (int e = tid; e < 768; e += 256){
    int p = e >> 8, i = e & 255;
    float acc = f2b[i];
    const float* wr = f2w + i*1024;
    for (int k = 0; k < 1024; k++) acc += hid[p*1024 + k]*wr[k];
    s2buf[e] += acc;
  }
  __syncthreads();

  finalv[tid] = fusedv[tid] + (s2buf[tid] + s2buf[256+tid] + s2buf[512+tid])*(1.f/3.f);
  __syncthreads();

  {
    float acc = e1b[tid];
    const float* wr = e1w + tid*256;
    for (int k = 0; k < 256; k++) acc += finalv[k]*wr[k];
    evh[tid] = geluf(acc);
  }
  __syncthreads();
  if (tid < 7){
    float acc = e2b[tid];
    const float* wr = e2w + tid*256;
    for (int k = 0; k < 256; k++) acc += evh[k]*wr[k];
    sv[tid] = softplusf_(acc);
  }
  __syncthreads();
  if (tid == 0){
    float s = 0.f;
    for (int j = 0; j < 7; j++) s += sv[j] + 1.f;
    sv[8] = s;
  }
  if (tid < 128){
    float acc = t1b[tid];
    const float* wr = t1w + tid*256;
    for (int k = 0; k < 256; k++) acc += finalv[k]*wr[k];
    tth[tid] = geluf(acc);
  }
  __syncthreads();
  if (tid < 12){
    float acc = t2b[tid];
    const float* wr = t2w + tid*128;
    for (int k = 0; k < 128; k++) acc += tth[k]*wr[k];
    sv[16 + tid] = acc;
  }
  __syncthreads();

  float* ob = out + b*162;
  if (tid < 7){
    float ev = sv[tid], al = ev + 1.f;
    ob[tid] = al / sv[8];
    ob[7 + tid] = ev;
    ob[14 + tid] = al;
  }
  if (tid == 0) ob[21] = 7.f / sv[8];
  if (tid < 6){
    ob[22 + tid] = softplusf_(sv[16 + tid]);
    ob[28 + tid] = expf(0.5f*sv[22 + tid]);
  }
  if (tid < 128){
    float acc = eb[tid];
    const float* wr = ew + tid*256;
    for (int k = 0; k < 256; k++) acc += finalv[k]*wr[k];
    ob[34 + tid] = acc;
  }
}

// ---------------------------------------------------------------------------
extern "C" void kernel_launch(void* const* d_in, const int* in_sizes, int n_in,
                              void* d_out, int out_size, void* d_ws, size_t ws_size,
                              hipStream_t stream)
{
  const float* x         = (const float*)d_in[0];
  const float* in_w      = (const float*)d_in[1];
  const float* in_b      = (const float*)d_in[2];
  const float* in_ln_g   = (const float*)d_in[3];
  const float* in_ln_b   = (const float*)d_in[4];
  const float* mb_ln_g   = (const float*)d_in[5];
  const float* mb_ln_b   = (const float*)d_in[6];
  const float* mb_in_w   = (const float*)d_in[7];
  const float* mb_conv_w = (const float*)d_in[8];
  const float* mb_conv_b = (const float*)d_in[9];
  const float* mb_xp_w   = (const float*)d_in[10];
  const float* mb_dt_w   = (const float*)d_in[11];
  const float* mb_dt_b   = (const float*)d_in[12];
  const float* mb_Alog   = (const float*)d_in[13];
  const float* mb_D      = (const float*)d_in[14];
  const float* mb_out_w  = (const float*)d_in[15];
  const float* sc_ln_g   = (const float*)d_in[16];
  const float* sc_ln_b   = (const float*)d_in[17];
  const float* sc_in_w   = (const float*)d_in[18];
  const float* sc_conv_w = (const float*)d_in[19];
  const float* sc_conv_b = (const float*)d_in[20];
  const float* sc_xp_w   = (const float*)d_in[21];
  const float* sc_dt_w   = (const float*)d_in[22];
  const float* sc_dt_b   = (const float*)d_in[23];
  const float* sc_Alog   = (const float*)d_in[24];
  const float* sc_D      = (const float*)d_in[25];
  const float* sc_out_w  = (const float*)d_in[26];
  const float* fus_qkv_w = (const float*)d_in[27];
  const float* fus_qkv_b = (const float*)d_in[28];
  const float* fus_out_w = (const float*)d_in[29];
  const float* fus_out_b = (const float*)d_in[30];
  const float* ms_out_w  = (const float*)d_in[31];
  const float* ms_out_b  = (const float*)d_in[32];
  const float* sa_ln1_g  = (const float*)d_in[33];
  const float* sa_ln1_b  = (const float*)d_in[34];
  const float* sa_ln2_g  = (const float*)d_in[35];
  const float* sa_ln2_b  = (const float*)d_in[36];
  const float* sa_qkv_w  = (const float*)d_in[37];
  const float* sa_qkv_b  = (const float*)d_in[38];
  const float* sa_out_w  = (const float*)d_in[39];
  const float* sa_out_b  = (const float*)d_in[40];
  const float* sa_ff1_w  = (const float*)d_in[41];
  const float* sa_ff1_b  = (const float*)d_in[42];
  const float* sa_ff2_w  = (const float*)d_in[43];
  const float* sa_ff2_b  = (const float*)d_in[44];
  const float* ev1_w     = (const float*)d_in[45];
  const float* ev1_b     = (const float*)d_in[46];
  const float* ev2_w     = (const float*)d_in[47];
  const float* ev2_b     = (const float*)d_in[48];
  const float* ttf1_w    = (const float*)d_in[49];
  const float* ttf1_b    = (const float*)d_in[50];
  const float* ttf2_w    = (const float*)d_in[51];
  const float* ttf2_b    = (const float*)d_in[52];
  const float* emb_w     = (const float*)d_in[53];
  const float* emb_b     = (const float*)d_in[54];

  float* ws = (float*)d_ws;
  float* h     = ws;                   // 4*1024*256   = 1,048,576
  float* xn    = h  + 1048576;         // 1,048,576
  float* uz    = xn + 1048576;         // 4*1024*1024  = 4,194,304
  float* uc    = uz + 4194304;         // 4*1024*512   = 2,097,152
  float* dtb_  = uc + 2097152;         // 2,097,152
  float* xd    = dtb_ + 2097152;       // 4*1024*48    = 196,608
  float* yg    = xd + 196608;          // 2,097,152
  float* stack = yg + 2097152;         // 3,072

  k_inproj<<<4096, 256, 0, stream>>>(x, in_w, in_b, in_ln_g, in_ln_b, h);

  for (int l = 0; l < 4; l++){
    k_ln<<<4096, 256, 0, stream>>>(h, mb_ln_g + l*256, mb_ln_b + l*256, xn, 1024, 0);
    {
      dim3 g(16, 64);
      k_gemm<0><<<g, 256, 0, stream>>>(xn, mb_in_w + l*262144, uz,
                                       nullptr, 1, 0, nullptr, 0, 0.f, 4096, 1024, 256);
    }
    k_conv<<<4096, 256, 0, stream>>>(uz, mb_conv_w + l*2048, mb_conv_b + l*512, uc, 1024);
    {
      dim3 g(1, 64);
      k_gemm<0><<<g, 256, 0, stream>>>(uc, mb_xp_w + l*24576, xd,
                                       nullptr, 1, 0, nullptr, 0, 0.f, 4096, 48, 512);
    }
    k_dt<<<4096, 256, 0, stream>>>(xd, mb_dt_w + l*8192, mb_dt_b + l*512, dtb_, 48);
    {
      dim3 g(32, 4);
      k_scan2<16><<<g, 256, 0, stream>>>(dtb_, uc, uz, xd, mb_Alog + l*8192, mb_D + l*512,
                                         yg, 1024, 48);
    }
    {
      dim3 g(4, 64);
      k_gemm<1><<<g, 256, 0, stream>>>(yg, mb_out_w + l*131072, h,
                                       h, 1024, 0, nullptr, 0, 0.f, 4096, 256, 512);
    }
  }

  k_zero<<<12, 256, 0, stream>>>(stack, 3072);
  const int scales[3] = {5, 20, 50};
  for (int i = 0; i < 3; i++){
    int s = scales[i];
    int rows = 4*s;
    int mb = (rows + 63)/64;
    k_ln<<<rows, 256, 0, stream>>>(h, sc_ln_g + i*256, sc_ln_b + i*256, xn, s, 1024 - s);
    {
      dim3 g(16, mb);
      k_gemm<0><<<g, 256, 0, stream>>>(xn, sc_in_w + i*262144, uz,
                                       nullptr, 1, 0, nullptr, 0, 0.f, rows, 1024, 256);
    }
    k_conv<<<rows, 256, 0, stream>>>(uz, sc_conv_w + i*2048, sc_conv_b + i*512, uc, s);
    {
      dim3 g(1, mb);
      k_gemm<0><<<g, 256, 0, stream>>>(uc, sc_xp_w + i*16384, xd,
                                       nullptr, 1, 0, nullptr, 0, 0.f, rows, 32, 512);
    }
    k_dt<<<rows, 256, 0, stream>>>(xd, sc_dt_w + i*8192, sc_dt_b + i*512, dtb_, 32);
    {
      dim3 g(32, 4);
      k_scan2<8><<<g, 128, 0, stream>>>(dtb_, uc, uz, xd, sc_Alog + i*4096, sc_D + i*512,
                                        yg, s, 32);
    }
    {
      dim3 g(4, mb);
      k_gemm<2><<<g, 256, 0, stream>>>(yg, sc_out_w + i*131072, nullptr,
                                       h, s, 1024 - s, stack, i*256, 1.f/(float)s,
                                       rows, 256, 512);
    }
  }

  k_tail<<<4, 256, 0, stream>>>(stack,
      fus_qkv_w, fus_qkv_b, fus_out_w, fus_out_b,
      ms_out_w, ms_out_b,
      sa_ln1_g, sa_ln1_b, sa_ln2_g, sa_ln2_b,
      sa_qkv_w, sa_qkv_b, sa_out_w, sa_out_b,
      sa_ff1_w, sa_ff1_b, sa_ff2_w, sa_ff2_b,
      ev1_w, ev1_b, ev2_w, ev2_b,
      ttf1_w, ttf1_b, ttf2_w, ttf2_b,
      emb_w, emb_b,
      (float*)d_out);
}

// Round 3
// 1905.479 us; speedup vs baseline: 1.7854x; 1.2316x over previous
//
#include <hip/hip_runtime.h>
#include <math.h>

// ---------------------------------------------------------------------------
// MambaPredictor forward. R2: bf16-MFMA GEMMs + parallelized tail.
// B=4 L=1024 NF=64 DM=256 DS=16 SCS=8 NL=4 DI=512 DTR=16 DC=4 NFM=6 NH=4
// ---------------------------------------------------------------------------

typedef short short8v __attribute__((ext_vector_type(8)));
typedef float f32x4   __attribute__((ext_vector_type(4)));

__device__ __forceinline__ float geluf(float x){ return 0.5f*x*(1.0f + erff(x*0.70710678118654752f)); }
__device__ __forceinline__ float softplusf_(float x){ return (x > 20.f) ? x : log1pf(expf(x)); }
__device__ __forceinline__ unsigned short f2bf(float f){
  unsigned int u = __float_as_uint(f);
  unsigned int r = (u + 0x7FFFu + ((u >> 16) & 1u)) >> 16;
  return (unsigned short)r;
}

// ---------------- fp32 -> bf16 bulk convert --------------------------------
__global__ __launch_bounds__(256) void k_f2b(const float* __restrict__ s,
                                             unsigned short* __restrict__ d, int n){
  int i = (blockIdx.x*256 + threadIdx.x)*4;
  if (i < n){
    float4 v = *(const float4*)(s + i);
    *(ushort4*)(d + i) = make_ushort4(f2bf(v.x), f2bf(v.y), f2bf(v.z), f2bf(v.w));
  }
}

// ---------------- initial: h = gelu(LN(x @ in_w^T + in_b)) -----------------
__global__ __launch_bounds__(256) void k_inproj(
    const float* __restrict__ x, const float* __restrict__ w,
    const float* __restrict__ b, const float* __restrict__ g,
    const float* __restrict__ beta, float* __restrict__ h)
{
  __shared__ float xr[64];
  __shared__ float r1[4], r2[4];
  int row = blockIdx.x;
  int tid = threadIdx.x;
  if (tid < 64) xr[tid] = x[row*64 + tid];
  __syncthreads();
  float acc = b[tid];
  const float* wr = w + tid*64;
  #pragma unroll
  for (int k = 0; k < 64; k++) acc += xr[k]*wr[k];
  float s1 = acc, s2 = acc*acc;
  #pragma unroll
  for (int o = 32; o > 0; o >>= 1){ s1 += __shfl_down(s1,o,64); s2 += __shfl_down(s2,o,64); }
  if ((tid & 63) == 0){ r1[tid>>6] = s1; r2[tid>>6] = s2; }
  __syncthreads();
  float S1 = r1[0]+r1[1]+r1[2]+r1[3];
  float S2 = r2[0]+r2[1]+r2[2]+r2[3];
  float m = S1*(1.f/256.f);
  float var = S2*(1.f/256.f) - m*m;
  float xn = (acc - m)*rsqrtf(var + 1e-5f)*g[tid] + beta[tid];
  h[row*256 + tid] = geluf(xn);
}

// ---------------- LayerNorm over 256 -> bf16, gather rows from h -----------
__global__ __launch_bounds__(256) void k_ln(
    const float* __restrict__ src, const float* __restrict__ g, const float* __restrict__ beta,
    unsigned short* __restrict__ dst, int rows_per_b, int src_off)
{
  __shared__ float r1[4], r2[4];
  int r = blockIdx.x, tid = threadIdx.x;
  int b = r / rows_per_b, t = r % rows_per_b;
  float v = src[(b*1024 + src_off + t)*256 + tid];
  float s1 = v, s2 = v*v;
  #pragma unroll
  for (int o = 32; o > 0; o >>= 1){ s1 += __shfl_down(s1,o,64); s2 += __shfl_down(s2,o,64); }
  if ((tid & 63) == 0){ r1[tid>>6] = s1; r2[tid>>6] = s2; }
  __syncthreads();
  float S1 = r1[0]+r1[1]+r1[2]+r1[3];
  float S2 = r2[0]+r2[1]+r2[2]+r2[3];
  float m = S1*(1.f/256.f);
  float var = S2*(1.f/256.f) - m*m;
  dst[r*256 + tid] = f2bf((v - m)*rsqrtf(var + 1e-5f)*g[tid] + beta[tid]);
}

// ---------------- MFMA GEMM: C = A(M,K)bf16 @ W(N,K)bf16^T, fp32 acc -------
// 64x64 tile, 4 waves of 32x32. Direct-global 16B fragment loads.
// MODE 0: C[r*N+c]=v ; MODE 1: C[r*N+c]=resid+v ; MODE 2: atomic pool add.
template<int MODE>
__global__ __launch_bounds__(256) void k_mm64(
    const unsigned short* __restrict__ A, const unsigned short* __restrict__ W,
    float* __restrict__ C,
    const float* __restrict__ resid, int rows_per_b, int res_off,
    float* __restrict__ pool_out, int pool_off, float pool_scale,
    int M, int N, int K)
{
  int tid = threadIdx.x;
  int wave = tid >> 6, lane = tid & 63;
  int mh = wave & 1, nh = wave >> 1;
  int m0 = blockIdx.y*64 + mh*32;
  int n0 = blockIdx.x*64 + nh*32;
  int lrow = lane & 15, kc = lane >> 4;
  f32x4 acc[2][2] = {{{0.f,0.f,0.f,0.f},{0.f,0.f,0.f,0.f}},{{0.f,0.f,0.f,0.f},{0.f,0.f,0.f,0.f}}};
  for (int k0 = 0; k0 < K; k0 += 32){
    short8v a[2], b[2];
    #pragma unroll
    for (int mi = 0; mi < 2; mi++){
      int r = m0 + mi*16 + lrow; r = min(r, M-1);
      a[mi] = *(const short8v*)(A + r*K + k0 + kc*8);
    }
    #pragma unroll
    for (int ni = 0; ni < 2; ni++){
      int c = n0 + ni*16 + lrow;
      b[ni] = *(const short8v*)(W + c*K + k0 + kc*8);
    }
    #pragma unroll
    for (int mi = 0; mi < 2; mi++)
      #pragma unroll
      for (int ni = 0; ni < 2; ni++)
        acc[mi][ni] = __builtin_amdgcn_mfma_f32_16x16x32_bf16(a[mi], b[ni], acc[mi][ni], 0, 0, 0);
  }
  int rb = kc*4;
  #pragma unroll
  for (int mi = 0; mi < 2; mi++){
    #pragma unroll
    for (int rr = 0; rr < 4; rr++){
      int grow = m0 + mi*16 + rb + rr;
      if (grow >= M) continue;
      int bb = grow / rows_per_b, t = grow % rows_per_b;
      #pragma unroll
      for (int ni = 0; ni < 2; ni++){
        int gcol = n0 + ni*16 + lrow;
        float v = acc[mi][ni][rr];
        if (MODE == 0){
          C[grow*N + gcol] = v;
        } else {
          float rv = resid[(bb*1024 + res_off + t)*256 + gcol] + v;
          if (MODE == 1) C[grow*N + gcol] = rv;
          else atomicAdd(&pool_out[bb*768 + pool_off + gcol], rv*pool_scale);
        }
      }
    }
  }
}

// ---- narrow MFMA GEMM: N = NT*16 (xp proj). One wave per 16-row m-tile ----
template<int NT>
__global__ __launch_bounds__(256) void k_mmN(
    const unsigned short* __restrict__ A, const unsigned short* __restrict__ W,
    float* __restrict__ C, int M, int K)
{
  int tid = threadIdx.x;
  int wave = tid >> 6, lane = tid & 63;
  int m0 = blockIdx.y*64 + wave*16;
  int lrow = lane & 15, kc = lane >> 4;
  f32x4 acc[NT];
  #pragma unroll
  for (int ni = 0; ni < NT; ni++) acc[ni] = (f32x4){0.f,0.f,0.f,0.f};
  for (int k0 = 0; k0 < K; k0 += 32){
    int r = m0 + lrow; r = min(r, M-1);
    short8v a = *(const short8v*)(A + r*K + k0 + kc*8);
    #pragma unroll
    for (int ni = 0; ni < NT; ni++){
      short8v b = *(const short8v*)(W + (ni*16 + lrow)*K + k0 + kc*8);
      acc[ni] = __builtin_amdgcn_mfma_f32_16x16x32_bf16(a, b, acc[ni], 0, 0, 0);
    }
  }
  int rb = kc*4;
  #pragma unroll
  for (int rr = 0; rr < 4; rr++){
    int grow = m0 + rb + rr;
    if (grow >= M) continue;
    #pragma unroll
    for (int ni = 0; ni < NT; ni++)
      C[grow*(NT*16) + ni*16 + lrow] = acc[ni][rr];
  }
}

// ---------------- depthwise causal conv (DC=4) + SiLU ----------------------
__global__ __launch_bounds__(256) void k_conv(
    const float* __restrict__ uz, const float* __restrict__ cw, const float* __restrict__ cb,
    float* __restrict__ uc, unsigned short* __restrict__ ucb, int Lseq)
{
  int row = blockIdx.x;
  int t = row % Lseq;
  int tid = threadIdx.x;
  for (int d = tid; d < 512; d += 256){
    float acc = cb[d];
    const float* w = cw + d*4;
    #pragma unroll
    for (int k = 0; k < 4; k++){
      int ts = t - 3 + k;
      if (ts >= 0) acc += uz[(row - (3-k))*1024 + d]*w[k];
    }
    float s = acc/(1.f + expf(-acc));
    uc[row*512 + d] = s;
    ucb[row*512 + d] = f2bf(s);
  }
}

// ---------------- dt = softplus(xd[:16] @ dtw^T + dtb) ---------------------
__global__ __launch_bounds__(256) void k_dt(
    const float* __restrict__ xd, const float* __restrict__ dtw, const float* __restrict__ dtb,
    float* __restrict__ dt, int xdld)
{
  __shared__ float sx[16];
  int row = blockIdx.x, tid = threadIdx.x;
  if (tid < 16) sx[tid] = xd[row*xdld + tid];
  __syncthreads();
  for (int d = tid; d < 512; d += 256){
    float acc = dtb[d];
    const float* w = dtw + d*16;
    #pragma unroll
    for (int j = 0; j < 16; j++) acc += sx[j]*w[j];
    dt[row*512 + d] = softplusf_(acc);
  }
}

// ---------------- selective scan + gate -> bf16 yg -------------------------
template<int DS>
__global__ __launch_bounds__(256) void k_scan2(
    const float* __restrict__ dt, const float* __restrict__ uc, const float* __restrict__ uz,
    const float* __restrict__ xd, const float* __restrict__ Alog, const float* __restrict__ Dp,
    unsigned short* __restrict__ yg, int Lseq, int xdld)
{
  const int TC = 32;
  const int QBC = (2*DS)/4;
  __shared__ float sdt[TC][16], suc[TC][16], sz[TC][16], sy[TC][16];
  __shared__ float sBC[TC][2*DS];
  int dblk = blockIdx.x, b = blockIdx.y;
  int nth = blockDim.x;
  int tid = threadIdx.x;
  int di = tid / DS, n = tid % DS;
  int d = dblk*16 + di;
  float A = -__expf(Alog[d*DS + n]);
  float Dv = Dp[d];
  float h = 0.f;
  for (int t0 = 0; t0 < Lseq; t0 += TC){
    int tcnt = min(TC, Lseq - t0);
    for (int e = tid; e < tcnt*4; e += nth){
      int tt = e >> 2, q = e & 3;
      long row = (long)(b*Lseq + t0 + tt);
      *(float4*)&sdt[tt][q*4] = *(const float4*)(dt + row*512 + dblk*16 + q*4);
      *(float4*)&suc[tt][q*4] = *(const float4*)(uc + row*512 + dblk*16 + q*4);
      *(float4*)&sz[tt][q*4]  = *(const float4*)(uz + row*1024 + 512 + dblk*16 + q*4);
    }
    for (int e = tid; e < tcnt*QBC; e += nth){
      int tt = e / QBC, q = e % QBC;
      long row = (long)(b*Lseq + t0 + tt);
      *(float4*)&sBC[tt][q*4] = *(const float4*)(xd + row*xdld + 16 + q*4);
    }
    __syncthreads();
    float da[TC], bu[TC];
    #pragma unroll
    for (int tt = 0; tt < TC; tt++){
      float dtv = sdt[tt][di];
      da[tt] = __expf(dtv*A);
      bu[tt] = dtv*suc[tt][di]*sBC[tt][n];
    }
    #pragma unroll
    for (int tt = 0; tt < TC; tt++){
      if (tt < tcnt){
        h = fmaf(da[tt], h, bu[tt]);
        bu[tt] = h*sBC[tt][DS+n];
      }
    }
    #pragma unroll
    for (int tt = 0; tt < TC; tt++){
      float pv = bu[tt];
      #pragma unroll
      for (int m = DS>>1; m; m >>= 1) pv += __shfl_xor(pv, m, 64);
      if (n == 0 && tt < tcnt){
        float y = pv + suc[tt][di]*Dv;
        float zv = sz[tt][di];
        sy[tt][di] = y*(zv/(1.f + __expf(-zv)));
      }
    }
    __syncthreads();
    for (int e = tid; e < tcnt*4; e += nth){
      int tt = e >> 2, q = e & 3;
      long row = (long)(b*Lseq + t0 + tt);
      float4 v = *(float4*)&sy[tt][q*4];
      *(ushort4*)(yg + row*512 + dblk*16 + q*4) =
        make_ushort4(f2bf(v.x), f2bf(v.y), f2bf(v.z), f2bf(v.w));
    }
    __syncthreads();
  }
}

__global__ void k_zero(float* p, int n){
  int i = blockIdx.x*256 + threadIdx.x;
  if (i < n) p[i] = 0.f;
}

// ================== tail kernels ==========================================
// generic tiny GEMM: out(M,N) = act(A(M,K) @ W(N,K)^T + bias) [+ resid(M x256)]
template<int M, int ACT, int RES>
__global__ __launch_bounds__(256) void k_tg(
    const float* __restrict__ A, const float* __restrict__ W,
    const float* __restrict__ bias, float* __restrict__ out,
    const float* __restrict__ resid, int N, int K, int ostride, int ocoff)
{
  extern __shared__ float sx[];
  int tid = threadIdx.x;
  for (int e = tid*4; e < M*K; e += 1024)
    *(float4*)&sx[e] = *(const float4*)(A + e);
  __syncthreads();
  int c = blockIdx.x*256 + tid;
  if (c >= N) return;
  float acc[M];
  #pragma unroll
  for (int r = 0; r < M; r++) acc[r] = 0.f;
  for (int k = 0; k < K; k += 4){
    float4 w4 = *(const float4*)(W + c*K + k);
    #pragma unroll
    for (int r = 0; r < M; r++){
      float4 x4 = *(float4*)&sx[r*K + k];
      acc[r] = fmaf(x4.x,w4.x,fmaf(x4.y,w4.y,fmaf(x4.z,w4.z,fmaf(x4.w,w4.w,acc[r]))));
    }
  }
  float bv = bias[c];
  #pragma unroll
  for (int r = 0; r < M; r++){
    float v = acc[r] + bv;
    if (ACT == 1) v = geluf(v);
    if (RES == 1) v += resid[r*256 + c];
    out[r*ostride + ocoff + c] = v;
  }
}

// LN of one 256-wide row (grid = #rows)
__global__ __launch_bounds__(256) void k_t_ln(
    const float* __restrict__ src, const float* __restrict__ g, const float* __restrict__ b,
    float* __restrict__ dst)
{
  __shared__ float r1[4], r2[4];
  int r = blockIdx.x, tid = threadIdx.x;
  float v = src[r*256 + tid];
  float s1 = v, s2 = v*v;
  #pragma unroll
  for (int o = 32; o > 0; o >>= 1){ s1 += __shfl_down(s1,o,64); s2 += __shfl_down(s2,o,64); }
  if ((tid & 63) == 0){ r1[tid>>6] = s1; r2[tid>>6] = s2; }
  __syncthreads();
  float S1 = r1[0]+r1[1]+r1[2]+r1[3];
  float S2 = r2[0]+r2[1]+r2[2]+r2[3];
  float m = S1*(1.f/256.f);
  float var = S2*(1.f/256.f) - m*m;
  dst[r*256 + tid] = (v - m)*rsqrtf(var + 1e-5f)*g[tid] + b[tid];
}

// attention core on 3-token seq, 4 heads (grid = B)
__global__ __launch_bounds__(256) void k_t_att(
    const float* __restrict__ qkv, float* __restrict__ ov)
{
  __shared__ float att[36];
  int b = blockIdx.x, tid = threadIdx.x;
  if (tid < 36){
    int hh = tid/9, r = (tid%9)/3, c = tid%3;
    float s = 0.f;
    const float* qp = qkv + (b*3 + r)*768 + hh*64;
    const float* kp = qkv + (b*3 + c)*768 + 256 + hh*64;
    for (int k = 0; k < 64; k++) s += qp[k]*kp[k];
    att[hh*9 + r*3 + c] = s*0.125f;
  }
  __syncthreads();
  if (tid < 12){
    int hh = tid/3, r = tid%3;
    float a0 = att[hh*9+r*3+0], a1 = att[hh*9+r*3+1], a2 = att[hh*9+r*3+2];
    float m = fmaxf(a0, fmaxf(a1, a2));
    float e0 = expf(a0-m), e1 = expf(a1-m), e2 = expf(a2-m);
    float s = e0+e1+e2;
    att[hh*9+r*3+0] = e0/s; att[hh*9+r*3+1] = e1/s; att[hh*9+r*3+2] = e2/s;
  }
  __syncthreads();
  for (int e = tid; e < 768; e += 256){
    int p = e >> 8, i = e & 255, hh = i >> 6;
    ov[(b*3 + p)*256 + i] = att[hh*9+p*3+0]*qkv[(b*3+0)*768+512+i]
                          + att[hh*9+p*3+1]*qkv[(b*3+1)*768+512+i]
                          + att[hh*9+p*3+2]*qkv[(b*3+2)*768+512+i];
  }
}

// finalv = fusedv + mean over 3 rows of s2f (grid = B)
__global__ __launch_bounds__(256) void k_t_final(
    const float* __restrict__ fusedv, const float* __restrict__ s2f, float* __restrict__ finalv)
{
  int b = blockIdx.x, c = threadIdx.x;
  finalv[b*256 + c] = fusedv[b*256 + c] +
    (s2f[(b*3+0)*256 + c] + s2f[(b*3+1)*256 + c] + s2f[(b*3+2)*256 + c])*(1.f/3.f);
}

// evidential + ttf head combine (grid = B)
__global__ __launch_bounds__(64) void k_t_fin(
    const float* __restrict__ evraw, const float* __restrict__ ttraw, float* __restrict__ out)
{
  __shared__ float ev[7];
  __shared__ float S;
  int b = blockIdx.x, tid = threadIdx.x;
  if (tid < 7) ev[tid] = softplusf_(evraw[b*7 + tid]);
  __syncthreads();
  if (tid == 0){
    float s = 0.f;
    for (int j = 0; j < 7; j++) s += ev[j] + 1.f;
    S = s;
  }
  __syncthreads();
  float* ob = out + b*162;
  if (tid < 7){
    float al = ev[tid] + 1.f;
    ob[tid] = al / S;
    ob[7 + tid] = ev[tid];
    ob[14 + tid] = al;
  }
  if (tid == 0) ob[21] = 7.f / S;
  if (tid < 6){
    ob[22 + tid] = softplusf_(ttraw[b*12 + tid]);
    ob[28 + tid] = expf(0.5f*ttraw[b*12 + 6 + tid]);
  }
}

// ---------------------------------------------------------------------------
extern "C" void kernel_launch(void* const* d_in, const int* in_sizes, int n_in,
                              void* d_out, int out_size, void* d_ws, size_t ws_size,
                              hipStream_t stream)
{
  const float* x         = (const float*)d_in[0];
  const float* in_w      = (const float*)d_in[1];
  const float* in_b      = (const float*)d_in[2];
  const float* in_ln_g   = (const float*)d_in[3];
  const float* in_ln_b   = (const float*)d_in[4];
  const float* mb_ln_g   = (const float*)d_in[5];
  const float* mb_ln_b   = (const float*)d_in[6];
  const float* mb_in_w   = (const float*)d_in[7];
  const float* mb_conv_w = (const float*)d_in[8];
  const float* mb_conv_b = (const float*)d_in[9];
  const float* mb_xp_w   = (const float*)d_in[10];
  const float* mb_dt_w   = (const float*)d_in[11];
  const float* mb_dt_b   = (const float*)d_in[12];
  const float* mb_Alog   = (const float*)d_in[13];
  const float* mb_D      = (const float*)d_in[14];
  const float* mb_out_w  = (const float*)d_in[15];
  const float* sc_ln_g   = (const float*)d_in[16];
  const float* sc_ln_b   = (const float*)d_in[17];
  const float* sc_in_w   = (const float*)d_in[18];
  const float* sc_conv_w = (const float*)d_in[19];
  const float* sc_conv_b = (const float*)d_in[20];
  const float* sc_xp_w   = (const float*)d_in[21];
  const float* sc_dt_w   = (const float*)d_in[22];
  const float* sc_dt_b   = (const float*)d_in[23];
  const float* sc_Alog   = (const float*)d_in[24];
  const float* sc_D      = (const float*)d_in[25];
  const float* sc_out_w  = (const float*)d_in[26];
  const float* fus_qkv_w = (const float*)d_in[27];
  const float* fus_qkv_b = (const float*)d_in[28];
  const float* fus_out_w = (const float*)d_in[29];
  const float* fus_out_b = (const float*)d_in[30];
  const float* ms_out_w  = (const float*)d_in[31];
  const float* ms_out_b  = (const float*)d_in[32];
  const float* sa_ln1_g  = (const float*)d_in[33];
  const float* sa_ln1_b  = (const float*)d_in[34];
  const float* sa_ln2_g  = (const float*)d_in[35];
  const float* sa_ln2_b  = (const float*)d_in[36];
  const float* sa_qkv_w  = (const float*)d_in[37];
  const float* sa_qkv_b  = (const float*)d_in[38];
  const float* sa_out_w  = (const float*)d_in[39];
  const float* sa_out_b  = (const float*)d_in[40];
  const float* sa_ff1_w  = (const float*)d_in[41];
  const float* sa_ff1_b  = (const float*)d_in[42];
  const float* sa_ff2_w  = (const float*)d_in[43];
  const float* sa_ff2_b  = (const float*)d_in[44];
  const float* ev1_w     = (const float*)d_in[45];
  const float* ev1_b     = (const float*)d_in[46];
  const float* ev2_w     = (const float*)d_in[47];
  const float* ev2_b     = (const float*)d_in[48];
  const float* ttf1_w    = (const float*)d_in[49];
  const float* ttf1_b    = (const float*)d_in[50];
  const float* ttf2_w    = (const float*)d_in[51];
  const float* ttf2_b    = (const float*)d_in[52];
  const float* emb_w     = (const float*)d_in[53];
  const float* emb_b     = (const float*)d_in[54];

  float* ws = (float*)d_ws;
  // fp32 region
  float* h     = ws;                        // 1,048,576
  float* uz    = h    + 1048576;            // 4,194,304
  float* uc    = uz   + 4194304;            // 2,097,152
  float* dtb_  = uc   + 2097152;            // 2,097,152
  float* xd    = dtb_ + 2097152;            // 196,608
  float* stack = xd   + 196608;             // 4,096 (3,072 used)
  float* tb    = stack + 4096;              // tail buffers
  float* qkvF   = tb;            // 9216
  float* ovF    = qkvF + 9216;   // 3072
  float* moF    = ovF  + 3072;   // 3072
  float* fusedv = moF  + 3072;   // 1024
  float* lnbuf  = fusedv + 1024; // 3072
  float* qkvS   = lnbuf + 3072;  // 9216
  float* ovS    = qkvS + 9216;   // 3072
  float* s2     = ovS  + 3072;   // 3072
  float* ln2r   = s2   + 3072;   // 3072
  float* hid    = ln2r + 3072;   // 12288
  float* s2f    = hid  + 12288;  // 3072
  float* finalv = s2f  + 3072;   // 1024
  float* evh    = finalv + 1024; // 1024
  float* tth    = evh  + 1024;   // 512
  float* evraw  = tth  + 512;    // 32
  float* ttraw  = evraw + 32;    // 64
  float* fp32_end = ttraw + 64;
  // bf16 region
  unsigned short* bfb = (unsigned short*)fp32_end;
  unsigned short* xnb    = bfb;                  // 1,048,576
  unsigned short* ucb    = xnb + 1048576;        // 2,097,152
  unsigned short* ygb    = ucb + 2097152;        // 2,097,152
  unsigned short* wmbin  = ygb + 2097152;        // 1,048,576
  unsigned short* wmbout = wmbin + 1048576;      // 524,288
  unsigned short* wmbxp  = wmbout + 524288;      // 98,304
  unsigned short* wscin  = wmbxp + 98304;        // 786,432
  unsigned short* wscout = wscin + 786432;       // 393,216
  unsigned short* wscxp  = wscout + 393216;      // 49,152

  // ---- weight conversions (bf16) ----
  k_f2b<<<1024, 256, 0, stream>>>(mb_in_w,  wmbin,  1048576);
  k_f2b<<<512,  256, 0, stream>>>(mb_out_w, wmbout, 524288);
  k_f2b<<<96,   256, 0, stream>>>(mb_xp_w,  wmbxp,  98304);
  k_f2b<<<768,  256, 0, stream>>>(sc_in_w,  wscin,  786432);
  k_f2b<<<384,  256, 0, stream>>>(sc_out_w, wscout, 393216);
  k_f2b<<<48,   256, 0, stream>>>(sc_xp_w,  wscxp,  49152);

  k_inproj<<<4096, 256, 0, stream>>>(x, in_w, in_b, in_ln_g, in_ln_b, h);

  // ---- 4 main mamba layers ----
  for (int l = 0; l < 4; l++){
    k_ln<<<4096, 256, 0, stream>>>(h, mb_ln_g + l*256, mb_ln_b + l*256, xnb, 1024, 0);
    {
      dim3 g(16, 64);
      k_mm64<0><<<g, 256, 0, stream>>>(xnb, wmbin + l*262144, uz,
                                       nullptr, 1, 0, nullptr, 0, 0.f, 4096, 1024, 256);
    }
    k_conv<<<4096, 256, 0, stream>>>(uz, mb_conv_w + l*2048, mb_conv_b + l*512, uc, ucb, 1024);
    {
      dim3 g(1, 64);
      k_mmN<3><<<g, 256, 0, stream>>>(ucb, wmbxp + l*24576, xd, 4096, 512);
    }
    k_dt<<<4096, 256, 0, stream>>>(xd, mb_dt_w + l*8192, mb_dt_b + l*512, dtb_, 48);
    {
      dim3 g(32, 4);
      k_scan2<16><<<g, 256, 0, stream>>>(dtb_, uc, uz, xd, mb_Alog + l*8192, mb_D + l*512,
                                         ygb, 1024, 48);
    }
    {
      dim3 g(4, 64);
      k_mm64<1><<<g, 256, 0, stream>>>(ygb, wmbout + l*131072, h,
                                       h, 1024, 0, nullptr, 0, 0.f, 4096, 256, 512);
    }
  }

  // ---- scale mambas -> pooled stack ----
  k_zero<<<12, 256, 0, stream>>>(stack, 3072);
  const int scales[3] = {5, 20, 50};
  for (int i = 0; i < 3; i++){
    int s = scales[i];
    int rows = 4*s;
    int mt = (rows + 63)/64;
    k_ln<<<rows, 256, 0, stream>>>(h, sc_ln_g + i*256, sc_ln_b + i*256, xnb, s, 1024 - s);
    {
      dim3 g(16, mt);
      k_mm64<0><<<g, 256, 0, stream>>>(xnb, wscin + i*262144, uz,
                                       nullptr, 1, 0, nullptr, 0, 0.f, rows, 1024, 256);
    }
    k_conv<<<rows, 256, 0, stream>>>(uz, sc_conv_w + i*2048, sc_conv_b + i*512, uc, ucb, s);
    {
      dim3 g(1, mt);
      k_mmN<2><<<g, 256, 0, stream>>>(ucb, wscxp + i*16384, xd, rows, 512);
    }
    k_dt<<<rows, 256, 0, stream>>>(xd, sc_dt_w + i*8192, sc_dt_b + i*512, dtb_, 32);
    {
      dim3 g(32, 4);
      k_scan2<8><<<g, 128, 0, stream>>>(dtb_, uc, uz, xd, sc_Alog + i*4096, sc_D + i*512,
                                        ygb, s, 32);
    }
    {
      dim3 g(4, mt);
      k_mm64<2><<<g, 256, 0, stream>>>(ygb, wscout + i*131072, nullptr,
                                       h, s, 1024 - s, stack, i*256, 1.f/(float)s,
                                       rows, 256, 512);
    }
  }

  // ---- tail (parallel small kernels) ----
  float* dout = (float*)d_out;
  // fused path
  k_tg<12,0,0><<<3, 256, 12*256*4, stream>>>(stack, fus_qkv_w, fus_qkv_b, qkvF, nullptr, 768, 256, 768, 0);
  k_t_att<<<4, 256, 0, stream>>>(qkvF, ovF);
  k_tg<12,0,0><<<1, 256, 12*256*4, stream>>>(ovF, fus_out_w, fus_out_b, moF, nullptr, 256, 256, 256, 0);
  k_tg<4,0,0><<<1, 256, 4*768*4, stream>>>(moF, ms_out_w, ms_out_b, fusedv, nullptr, 256, 768, 256, 0);
  // sa path
  k_t_ln<<<12, 256, 0, stream>>>(stack, sa_ln1_g, sa_ln1_b, lnbuf);
  k_tg<12,0,0><<<3, 256, 12*256*4, stream>>>(lnbuf, sa_qkv_w, sa_qkv_b, qkvS, nullptr, 768, 256, 768, 0);
  k_t_att<<<4, 256, 0, stream>>>(qkvS, ovS);
  k_tg<12,0,1><<<1, 256, 12*256*4, stream>>>(ovS, sa_out_w, sa_out_b, s2, stack, 256, 256, 256, 0);
  k_t_ln<<<12, 256, 0, stream>>>(s2, sa_ln2_g, sa_ln2_b, ln2r);
  k_tg<12,1,0><<<4, 256, 12*256*4, stream>>>(ln2r, sa_ff1_w, sa_ff1_b, hid, nullptr, 1024, 256, 1024, 0);
  k_tg<12,0,1><<<1, 256, 12*1024*4, stream>>>(hid, sa_ff2_w, sa_ff2_b, s2f, s2, 256, 1024, 256, 0);
  k_t_final<<<4, 256, 0, stream>>>(fusedv, s2f, finalv);
  // heads
  k_tg<4,1,0><<<1, 256, 4*256*4, stream>>>(finalv, ev1_w, ev1_b, evh, nullptr, 256, 256, 256, 0);
  k_tg<4,0,0><<<1, 256, 4*256*4, stream>>>(evh, ev2_w, ev2_b, evraw, nullptr, 7, 256, 7, 0);
  k_tg<4,1,0><<<1, 256, 4*256*4, stream>>>(finalv, ttf1_w, ttf1_b, tth, nullptr, 128, 256, 128, 0);
  k_tg<4,0,0><<<1, 256, 4*128*4, stream>>>(tth, ttf2_w, ttf2_b, ttraw, nullptr, 12, 128, 12, 0);
  k_tg<4,0,0><<<1, 256, 4*256*4, stream>>>(finalv, emb_w, emb_b, dout, nullptr, 128, 256, 162, 34);
  k_t_fin<<<4, 64, 0, stream>>>(evraw, ttraw, dout);
}

// Round 4
// 1140.583 us; speedup vs baseline: 2.9828x; 1.6706x over previous
//
#include <hip/hip_runtime.h>
#include <math.h>

// ---------------------------------------------------------------------------
// MambaPredictor forward. R3: chunked-associative selective scan (3-pass).
// B=4 L=1024 NF=64 DM=256 DS=16 SCS=8 NL=4 DI=512 DTR=16 DC=4 NFM=6 NH=4
// ---------------------------------------------------------------------------

typedef short short8v __attribute__((ext_vector_type(8)));
typedef float f32x4   __attribute__((ext_vector_type(4)));

__device__ __forceinline__ float geluf(float x){ return 0.5f*x*(1.0f + erff(x*0.70710678118654752f)); }
__device__ __forceinline__ float softplusf_(float x){ return (x > 20.f) ? x : log1pf(expf(x)); }
__device__ __forceinline__ unsigned short f2bf(float f){
  unsigned int u = __float_as_uint(f);
  unsigned int r = (u + 0x7FFFu + ((u >> 16) & 1u)) >> 16;
  return (unsigned short)r;
}

// ---------------- fp32 -> bf16 bulk convert --------------------------------
__global__ __launch_bounds__(256) void k_f2b(const float* __restrict__ s,
                                             unsigned short* __restrict__ d, int n){
  int i = (blockIdx.x*256 + threadIdx.x)*4;
  if (i < n){
    float4 v = *(const float4*)(s + i);
    *(ushort4*)(d + i) = make_ushort4(f2bf(v.x), f2bf(v.y), f2bf(v.z), f2bf(v.w));
  }
}

// ---------------- initial: h = gelu(LN(x @ in_w^T + in_b)) -----------------
__global__ __launch_bounds__(256) void k_inproj(
    const float* __restrict__ x, const float* __restrict__ w,
    const float* __restrict__ b, const float* __restrict__ g,
    const float* __restrict__ beta, float* __restrict__ h)
{
  __shared__ float xr[64];
  __shared__ float r1[4], r2[4];
  int row = blockIdx.x;
  int tid = threadIdx.x;
  if (tid < 64) xr[tid] = x[row*64 + tid];
  __syncthreads();
  float acc = b[tid];
  const float* wr = w + tid*64;
  #pragma unroll
  for (int k = 0; k < 64; k++) acc += xr[k]*wr[k];
  float s1 = acc, s2 = acc*acc;
  #pragma unroll
  for (int o = 32; o > 0; o >>= 1){ s1 += __shfl_down(s1,o,64); s2 += __shfl_down(s2,o,64); }
  if ((tid & 63) == 0){ r1[tid>>6] = s1; r2[tid>>6] = s2; }
  __syncthreads();
  float S1 = r1[0]+r1[1]+r1[2]+r1[3];
  float S2 = r2[0]+r2[1]+r2[2]+r2[3];
  float m = S1*(1.f/256.f);
  float var = S2*(1.f/256.f) - m*m;
  float xn = (acc - m)*rsqrtf(var + 1e-5f)*g[tid] + beta[tid];
  h[row*256 + tid] = geluf(xn);
}

// ---------------- LayerNorm over 256 -> bf16, gather rows from h -----------
__global__ __launch_bounds__(256) void k_ln(
    const float* __restrict__ src, const float* __restrict__ g, const float* __restrict__ beta,
    unsigned short* __restrict__ dst, int rows_per_b, int src_off)
{
  __shared__ float r1[4], r2[4];
  int r = blockIdx.x, tid = threadIdx.x;
  int b = r / rows_per_b, t = r % rows_per_b;
  float v = src[(b*1024 + src_off + t)*256 + tid];
  float s1 = v, s2 = v*v;
  #pragma unroll
  for (int o = 32; o > 0; o >>= 1){ s1 += __shfl_down(s1,o,64); s2 += __shfl_down(s2,o,64); }
  if ((tid & 63) == 0){ r1[tid>>6] = s1; r2[tid>>6] = s2; }
  __syncthreads();
  float S1 = r1[0]+r1[1]+r1[2]+r1[3];
  float S2 = r2[0]+r2[1]+r2[2]+r2[3];
  float m = S1*(1.f/256.f);
  float var = S2*(1.f/256.f) - m*m;
  dst[r*256 + tid] = f2bf((v - m)*rsqrtf(var + 1e-5f)*g[tid] + beta[tid]);
}

// ---------------- MFMA GEMM: C = A(M,K)bf16 @ W(N,K)bf16^T, fp32 acc -------
template<int MODE>
__global__ __launch_bounds__(256) void k_mm64(
    const unsigned short* __restrict__ A, const unsigned short* __restrict__ W,
    float* __restrict__ C,
    const float* __restrict__ resid, int rows_per_b, int res_off,
    float* __restrict__ pool_out, int pool_off, float pool_scale,
    int M, int N, int K)
{
  int tid = threadIdx.x;
  int wave = tid >> 6, lane = tid & 63;
  int mh = wave & 1, nh = wave >> 1;
  int m0 = blockIdx.y*64 + mh*32;
  int n0 = blockIdx.x*64 + nh*32;
  int lrow = lane & 15, kc = lane >> 4;
  f32x4 acc[2][2] = {{{0.f,0.f,0.f,0.f},{0.f,0.f,0.f,0.f}},{{0.f,0.f,0.f,0.f},{0.f,0.f,0.f,0.f}}};
  for (int k0 = 0; k0 < K; k0 += 32){
    short8v a[2], b[2];
    #pragma unroll
    for (int mi = 0; mi < 2; mi++){
      int r = m0 + mi*16 + lrow; r = min(r, M-1);
      a[mi] = *(const short8v*)(A + r*K + k0 + kc*8);
    }
    #pragma unroll
    for (int ni = 0; ni < 2; ni++){
      int c = n0 + ni*16 + lrow;
      b[ni] = *(const short8v*)(W + c*K + k0 + kc*8);
    }
    #pragma unroll
    for (int mi = 0; mi < 2; mi++)
      #pragma unroll
      for (int ni = 0; ni < 2; ni++)
        acc[mi][ni] = __builtin_amdgcn_mfma_f32_16x16x32_bf16(a[mi], b[ni], acc[mi][ni], 0, 0, 0);
  }
  int rb = kc*4;
  #pragma unroll
  for (int mi = 0; mi < 2; mi++){
    #pragma unroll
    for (int rr = 0; rr < 4; rr++){
      int grow = m0 + mi*16 + rb + rr;
      if (grow >= M) continue;
      int bb = grow / rows_per_b, t = grow % rows_per_b;
      #pragma unroll
      for (int ni = 0; ni < 2; ni++){
        int gcol = n0 + ni*16 + lrow;
        float v = acc[mi][ni][rr];
        if (MODE == 0){
          C[grow*N + gcol] = v;
        } else {
          float rv = resid[(bb*1024 + res_off + t)*256 + gcol] + v;
          if (MODE == 1) C[grow*N + gcol] = rv;
          else atomicAdd(&pool_out[bb*768 + pool_off + gcol], rv*pool_scale);
        }
      }
    }
  }
}

// ---- narrow MFMA GEMM: N = NT*16 (xp proj). One wave per 16-row m-tile ----
template<int NT>
__global__ __launch_bounds__(256) void k_mmN(
    const unsigned short* __restrict__ A, const unsigned short* __restrict__ W,
    float* __restrict__ C, int M, int K)
{
  int tid = threadIdx.x;
  int wave = tid >> 6, lane = tid & 63;
  int m0 = blockIdx.y*64 + wave*16;
  int lrow = lane & 15, kc = lane >> 4;
  f32x4 acc[NT];
  #pragma unroll
  for (int ni = 0; ni < NT; ni++) acc[ni] = (f32x4){0.f,0.f,0.f,0.f};
  for (int k0 = 0; k0 < K; k0 += 32){
    int r = m0 + lrow; r = min(r, M-1);
    short8v a = *(const short8v*)(A + r*K + k0 + kc*8);
    #pragma unroll
    for (int ni = 0; ni < NT; ni++){
      short8v b = *(const short8v*)(W + (ni*16 + lrow)*K + k0 + kc*8);
      acc[ni] = __builtin_amdgcn_mfma_f32_16x16x32_bf16(a, b, acc[ni], 0, 0, 0);
    }
  }
  int rb = kc*4;
  #pragma unroll
  for (int rr = 0; rr < 4; rr++){
    int grow = m0 + rb + rr;
    if (grow >= M) continue;
    #pragma unroll
    for (int ni = 0; ni < NT; ni++)
      C[grow*(NT*16) + ni*16 + lrow] = acc[ni][rr];
  }
}

// ---------------- depthwise causal conv (DC=4) + SiLU ----------------------
__global__ __launch_bounds__(256) void k_conv(
    const float* __restrict__ uz, const float* __restrict__ cw, const float* __restrict__ cb,
    float* __restrict__ uc, unsigned short* __restrict__ ucb, int Lseq)
{
  int row = blockIdx.x;
  int t = row % Lseq;
  int tid = threadIdx.x;
  for (int d = tid; d < 512; d += 256){
    float acc = cb[d];
    const float* w = cw + d*4;
    #pragma unroll
    for (int k = 0; k < 4; k++){
      int ts = t - 3 + k;
      if (ts >= 0) acc += uz[(row - (3-k))*1024 + d]*w[k];
    }
    float s = acc/(1.f + expf(-acc));
    uc[row*512 + d] = s;
    ucb[row*512 + d] = f2bf(s);
  }
}

// ---------------- dt = softplus(xd[:16] @ dtw^T + dtb) ---------------------
__global__ __launch_bounds__(256) void k_dt(
    const float* __restrict__ xd, const float* __restrict__ dtw, const float* __restrict__ dtb,
    float* __restrict__ dt, int xdld)
{
  __shared__ float sx[16];
  int row = blockIdx.x, tid = threadIdx.x;
  if (tid < 16) sx[tid] = xd[row*xdld + tid];
  __syncthreads();
  for (int d = tid; d < 512; d += 256){
    float acc = dtb[d];
    const float* w = dtw + d*16;
    #pragma unroll
    for (int j = 0; j < 16; j++) acc += sx[j]*w[j];
    dt[row*512 + d] = softplusf_(acc);
  }
}

// ============ chunked selective scan (3-pass) ==============================
// thread owns one d-channel, all DS state dims in registers: no shuffles,
// DS independent fma chains per thread (ILP hides exp/fma latency).
// grid = (DI/64, B, NCH); block = 64.

// pass 1: local scan of chunk (h0=0) -> hend[(b,ch,d,n)], sdt[(b,ch,d)] = sum dt
template<int DS>
__global__ __launch_bounds__(64) void k_scan_p1(
    const float* __restrict__ dt, const float* __restrict__ uc,
    const float* __restrict__ xd, const float* __restrict__ Alog,
    float* __restrict__ hend, float* __restrict__ sdtb,
    int Lseq, int xdld, int NCH, int CL)
{
  const int Q = DS/4;
  __shared__ float sB[64][DS];
  int tid = threadIdx.x;
  int d = blockIdx.x*64 + tid;
  int b = blockIdx.y, ch = blockIdx.z;
  int t0 = ch*CL;
  float A[DS];
  #pragma unroll
  for (int n = 0; n < DS; n++) A[n] = -__expf(Alog[d*DS + n]);
  // stage B
  for (int e = tid; e < CL*Q; e += 64){
    int t = e/Q, q = e%Q;
    *(float4*)&sB[t][q*4] = *(const float4*)(xd + (b*Lseq + t0 + t)*xdld + 16 + q*4);
  }
  __syncthreads();
  float h[DS];
  #pragma unroll
  for (int n = 0; n < DS; n++) h[n] = 0.f;
  float Ssum = 0.f;
  for (int t = 0; t < CL; t++){
    int row = b*Lseq + t0 + t;
    float dtv = dt[row*512 + d];
    float uv  = uc[row*512 + d];
    Ssum += dtv;
    float du = dtv*uv;
    #pragma unroll
    for (int n = 0; n < DS; n++)
      h[n] = fmaf(__expf(dtv*A[n]), h[n], du*sB[t][n]);
  }
  int base = ((b*NCH + ch)*512 + d)*DS;
  #pragma unroll
  for (int q = 0; q < Q; q++)
    *(float4*)(hend + base + q*4) = make_float4(h[q*4], h[q*4+1], h[q*4+2], h[q*4+3]);
  sdtb[(b*NCH + ch)*512 + d] = Ssum;
}

// pass 2: sequential combine over chunks; one thread per (b,d,n). DS=16 only.
__global__ __launch_bounds__(256) void k_scomb(
    const float* __restrict__ hend, const float* __restrict__ sdtb,
    const float* __restrict__ Alog, float* __restrict__ hstart, int NCH)
{
  int idx = blockIdx.x*256 + threadIdx.x;       // b*8192 + d*16 + n
  int low = idx & 8191;
  int n = idx & 15, d = (idx >> 4) & 511, b = idx >> 13;
  float A = -__expf(Alog[d*16 + n]);
  float hs = 0.f;
  hstart[(b*NCH)*8192 + low] = 0.f;
  for (int c = 0; c < NCH-1; c++){
    float S  = sdtb[(b*NCH + c)*512 + d];
    float he = hend[(b*NCH + c)*8192 + low];
    hs = fmaf(__expf(A*S), hs, he);
    hstart[(b*NCH + c + 1)*8192 + low] = hs;
  }
}

// pass 3: re-scan chunk from true start state; fused C-dot + D-skip + gate.
template<int DS>
__global__ __launch_bounds__(64) void k_scan_p3(
    const float* __restrict__ dt, const float* __restrict__ uc,
    const float* __restrict__ uz, const float* __restrict__ xd,
    const float* __restrict__ Alog, const float* __restrict__ Dp,
    const float* __restrict__ hstart, unsigned short* __restrict__ yg,
    int Lseq, int xdld, int NCH, int CL, int init0)
{
  const int Q2 = DS/2;                  // float4s per row of [B|C]
  __shared__ float sBC[64][2*DS];
  int tid = threadIdx.x;
  int d = blockIdx.x*64 + tid;
  int b = blockIdx.y, ch = blockIdx.z;
  int t0 = ch*CL;
  float A[DS];
  #pragma unroll
  for (int n = 0; n < DS; n++) A[n] = -__expf(Alog[d*DS + n]);
  float Dv = Dp[d];
  for (int e = tid; e < CL*Q2; e += 64){
    int t = e/Q2, q = e%Q2;
    *(float4*)&sBC[t][q*4] = *(const float4*)(xd + (b*Lseq + t0 + t)*xdld + 16 + q*4);
  }
  __syncthreads();
  float h[DS];
  if (init0){
    #pragma unroll
    for (int n = 0; n < DS; n++) h[n] = 0.f;
  } else {
    int base = ((b*NCH + ch)*512 + d)*DS;
    #pragma unroll
    for (int q = 0; q < DS/4; q++){
      float4 v = *(const float4*)(hstart + base + q*4);
      h[q*4] = v.x; h[q*4+1] = v.y; h[q*4+2] = v.z; h[q*4+3] = v.w;
    }
  }
  for (int t = 0; t < CL; t++){
    int row = b*Lseq + t0 + t;
    float dtv = dt[row*512 + d];
    float uv  = uc[row*512 + d];
    float zv  = uz[row*1024 + 512 + d];
    float du = dtv*uv;
    float y = 0.f;
    #pragma unroll
    for (int n = 0; n < DS; n++){
      h[n] = fmaf(__expf(dtv*A[n]), h[n], du*sBC[t][n]);
      y = fmaf(h[n], sBC[t][DS+n], y);
    }
    y = fmaf(uv, Dv, y);
    float gate = zv/(1.f + __expf(-zv));
    yg[row*512 + d] = f2bf(y*gate);
  }
}

__global__ void k_zero(float* p, int n){
  int i = blockIdx.x*256 + threadIdx.x;
  if (i < n) p[i] = 0.f;
}

// ================== tail kernels ==========================================
template<int M, int ACT, int RES>
__global__ __launch_bounds__(256) void k_tg(
    const float* __restrict__ A, const float* __restrict__ W,
    const float* __restrict__ bias, float* __restrict__ out,
    const float* __restrict__ resid, int N, int K, int ostride, int ocoff)
{
  extern __shared__ float sx[];
  int tid = threadIdx.x;
  for (int e = tid*4; e < M*K; e += 1024)
    *(float4*)&sx[e] = *(const float4*)(A + e);
  __syncthreads();
  int c = blockIdx.x*256 + tid;
  if (c >= N) return;
  float acc[M];
  #pragma unroll
  for (int r = 0; r < M; r++) acc[r] = 0.f;
  for (int k = 0; k < K; k += 4){
    float4 w4 = *(const float4*)(W + c*K + k);
    #pragma unroll
    for (int r = 0; r < M; r++){
      float4 x4 = *(float4*)&sx[r*K + k];
      acc[r] = fmaf(x4.x,w4.x,fmaf(x4.y,w4.y,fmaf(x4.z,w4.z,fmaf(x4.w,w4.w,acc[r]))));
    }
  }
  float bv = bias[c];
  #pragma unroll
  for (int r = 0; r < M; r++){
    float v = acc[r] + bv;
    if (ACT == 1) v = geluf(v);
    if (RES == 1) v += resid[r*256 + c];
    out[r*ostride + ocoff + c] = v;
  }
}

__global__ __launch_bounds__(256) void k_t_ln(
    const float* __restrict__ src, const float* __restrict__ g, const float* __restrict__ b,
    float* __restrict__ dst)
{
  __shared__ float r1[4], r2[4];
  int r = blockIdx.x, tid = threadIdx.x;
  float v = src[r*256 + tid];
  float s1 = v, s2 = v*v;
  #pragma unroll
  for (int o = 32; o > 0; o >>= 1){ s1 += __shfl_down(s1,o,64); s2 += __shfl_down(s2,o,64); }
  if ((tid & 63) == 0){ r1[tid>>6] = s1; r2[tid>>6] = s2; }
  __syncthreads();
  float S1 = r1[0]+r1[1]+r1[2]+r1[3];
  float S2 = r2[0]+r2[1]+r2[2]+r2[3];
  float m = S1*(1.f/256.f);
  float var = S2*(1.f/256.f) - m*m;
  dst[r*256 + tid] = (v - m)*rsqrtf(var + 1e-5f)*g[tid] + b[tid];
}

__global__ __launch_bounds__(256) void k_t_att(
    const float* __restrict__ qkv, float* __restrict__ ov)
{
  __shared__ float att[36];
  int b = blockIdx.x, tid = threadIdx.x;
  if (tid < 36){
    int hh = tid/9, r = (tid%9)/3, c = tid%3;
    float s = 0.f;
    const float* qp = qkv + (b*3 + r)*768 + hh*64;
    const float* kp = qkv + (b*3 + c)*768 + 256 + hh*64;
    for (int k = 0; k < 64; k++) s += qp[k]*kp[k];
    att[hh*9 + r*3 + c] = s*0.125f;
  }
  __syncthreads();
  if (tid < 12){
    int hh = tid/3, r = tid%3;
    float a0 = att[hh*9+r*3+0], a1 = att[hh*9+r*3+1], a2 = att[hh*9+r*3+2];
    float m = fmaxf(a0, fmaxf(a1, a2));
    float e0 = expf(a0-m), e1 = expf(a1-m), e2 = expf(a2-m);
    float s = e0+e1+e2;
    att[hh*9+r*3+0] = e0/s; att[hh*9+r*3+1] = e1/s; att[hh*9+r*3+2] = e2/s;
  }
  __syncthreads();
  for (int e = tid; e < 768; e += 256){
    int p = e >> 8, i = e & 255, hh = i >> 6;
    ov[(b*3 + p)*256 + i] = att[hh*9+p*3+0]*qkv[(b*3+0)*768+512+i]
                          + att[hh*9+p*3+1]*qkv[(b*3+1)*768+512+i]
                          + att[hh*9+p*3+2]*qkv[(b*3+2)*768+512+i];
  }
}

__global__ __launch_bounds__(256) void k_t_final(
    const float* __restrict__ fusedv, const float* __restrict__ s2f, float* __restrict__ finalv)
{
  int b = blockIdx.x, c = threadIdx.x;
  finalv[b*256 + c] = fusedv[b*256 + c] +
    (s2f[(b*3+0)*256 + c] + s2f[(b*3+1)*256 + c] + s2f[(b*3+2)*256 + c])*(1.f/3.f);
}

__global__ __launch_bounds__(64) void k_t_fin(
    const float* __restrict__ evraw, const float* __restrict__ ttraw, float* __restrict__ out)
{
  __shared__ float ev[7];
  __shared__ float S;
  int b = blockIdx.x, tid = threadIdx.x;
  if (tid < 7) ev[tid] = softplusf_(evraw[b*7 + tid]);
  __syncthreads();
  if (tid == 0){
    float s = 0.f;
    for (int j = 0; j < 7; j++) s += ev[j] + 1.f;
    S = s;
  }
  __syncthreads();
  float* ob = out + b*162;
  if (tid < 7){
    float al = ev[tid] + 1.f;
    ob[tid] = al / S;
    ob[7 + tid] = ev[tid];
    ob[14 + tid] = al;
  }
  if (tid == 0) ob[21] = 7.f / S;
  if (tid < 6){
    ob[22 + tid] = softplusf_(ttraw[b*12 + tid]);
    ob[28 + tid] = expf(0.5f*ttraw[b*12 + 6 + tid]);
  }
}

// ---------------------------------------------------------------------------
extern "C" void kernel_launch(void* const* d_in, const int* in_sizes, int n_in,
                              void* d_out, int out_size, void* d_ws, size_t ws_size,
                              hipStream_t stream)
{
  const float* x         = (const float*)d_in[0];
  const float* in_w      = (const float*)d_in[1];
  const float* in_b      = (const float*)d_in[2];
  const float* in_ln_g   = (const float*)d_in[3];
  const float* in_ln_b   = (const float*)d_in[4];
  const float* mb_ln_g   = (const float*)d_in[5];
  const float* mb_ln_b   = (const float*)d_in[6];
  const float* mb_in_w   = (const float*)d_in[7];
  const float* mb_conv_w = (const float*)d_in[8];
  const float* mb_conv_b = (const float*)d_in[9];
  const float* mb_xp_w   = (const float*)d_in[10];
  const float* mb_dt_w   = (const float*)d_in[11];
  const float* mb_dt_b   = (const float*)d_in[12];
  const float* mb_Alog   = (const float*)d_in[13];
  const float* mb_D      = (const float*)d_in[14];
  const float* mb_out_w  = (const float*)d_in[15];
  const float* sc_ln_g   = (const float*)d_in[16];
  const float* sc_ln_b   = (const float*)d_in[17];
  const float* sc_in_w   = (const float*)d_in[18];
  const float* sc_conv_w = (const float*)d_in[19];
  const float* sc_conv_b = (const float*)d_in[20];
  const float* sc_xp_w   = (const float*)d_in[21];
  const float* sc_dt_w   = (const float*)d_in[22];
  const float* sc_dt_b   = (const float*)d_in[23];
  const float* sc_Alog   = (const float*)d_in[24];
  const float* sc_D      = (const float*)d_in[25];
  const float* sc_out_w  = (const float*)d_in[26];
  const float* fus_qkv_w = (const float*)d_in[27];
  const float* fus_qkv_b = (const float*)d_in[28];
  const float* fus_out_w = (const float*)d_in[29];
  const float* fus_out_b = (const float*)d_in[30];
  const float* ms_out_w  = (const float*)d_in[31];
  const float* ms_out_b  = (const float*)d_in[32];
  const float* sa_ln1_g  = (const float*)d_in[33];
  const float* sa_ln1_b  = (const float*)d_in[34];
  const float* sa_ln2_g  = (const float*)d_in[35];
  const float* sa_ln2_b  = (const float*)d_in[36];
  const float* sa_qkv_w  = (const float*)d_in[37];
  const float* sa_qkv_b  = (const float*)d_in[38];
  const float* sa_out_w  = (const float*)d_in[39];
  const float* sa_out_b  = (const float*)d_in[40];
  const float* sa_ff1_w  = (const float*)d_in[41];
  const float* sa_ff1_b  = (const float*)d_in[42];
  const float* sa_ff2_w  = (const float*)d_in[43];
  const float* sa_ff2_b  = (const float*)d_in[44];
  const float* ev1_w     = (const float*)d_in[45];
  const float* ev1_b     = (const float*)d_in[46];
  const float* ev2_w     = (const float*)d_in[47];
  const float* ev2_b     = (const float*)d_in[48];
  const float* ttf1_w    = (const float*)d_in[49];
  const float* ttf1_b    = (const float*)d_in[50];
  const float* ttf2_w    = (const float*)d_in[51];
  const float* ttf2_b    = (const float*)d_in[52];
  const float* emb_w     = (const float*)d_in[53];
  const float* emb_b     = (const float*)d_in[54];

  const int NCH = 16, CL = 64;   // 1024 = 16 x 64

  float* ws = (float*)d_ws;
  // fp32 region
  float* h     = ws;                        // 1,048,576
  float* uz    = h    + 1048576;            // 4,194,304
  float* uc    = uz   + 4194304;            // 2,097,152
  float* dtb_  = uc   + 2097152;            // 2,097,152
  float* xd    = dtb_ + 2097152;            // 196,608
  float* stack = xd   + 196608;             // 4,096 (3,072 used)
  float* tb    = stack + 4096;              // tail buffers
  float* qkvF   = tb;            // 9216
  float* ovF    = qkvF + 9216;   // 3072
  float* moF    = ovF  + 3072;   // 3072
  float* fusedv = moF  + 3072;   // 1024
  float* lnbuf  = fusedv + 1024; // 3072
  float* qkvS   = lnbuf + 3072;  // 9216
  float* ovS    = qkvS + 9216;   // 3072
  float* s2     = ovS  + 3072;   // 3072
  float* ln2r   = s2   + 3072;   // 3072
  float* hid    = ln2r + 3072;   // 12288
  float* s2f    = hid  + 12288;  // 3072
  float* finalv = s2f  + 3072;   // 1024
  float* evh    = finalv + 1024; // 1024
  float* tth    = evh  + 1024;   // 512
  float* evraw  = tth  + 512;    // 32
  float* ttraw  = evraw + 32;    // 64
  // scan chunk buffers
  float* hend   = ttraw + 64;            // 4*16*512*16 = 524,288
  float* hstart = hend + 524288;         // 524,288
  float* sdtb   = hstart + 524288;       // 4*16*512 = 32,768
  float* fp32_end = sdtb + 32768;
  // bf16 region
  unsigned short* bfb = (unsigned short*)fp32_end;
  unsigned short* xnb    = bfb;                  // 1,048,576
  unsigned short* ucb    = xnb + 1048576;        // 2,097,152
  unsigned short* ygb    = ucb + 2097152;        // 2,097,152
  unsigned short* wmbin  = ygb + 2097152;        // 1,048,576
  unsigned short* wmbout = wmbin + 1048576;      // 524,288
  unsigned short* wmbxp  = wmbout + 524288;      // 98,304
  unsigned short* wscin  = wmbxp + 98304;        // 786,432
  unsigned short* wscout = wscin + 786432;       // 393,216
  unsigned short* wscxp  = wscout + 393216;      // 49,152

  // ---- weight conversions (bf16) ----
  k_f2b<<<1024, 256, 0, stream>>>(mb_in_w,  wmbin,  1048576);
  k_f2b<<<512,  256, 0, stream>>>(mb_out_w, wmbout, 524288);
  k_f2b<<<96,   256, 0, stream>>>(mb_xp_w,  wmbxp,  98304);
  k_f2b<<<768,  256, 0, stream>>>(sc_in_w,  wscin,  786432);
  k_f2b<<<384,  256, 0, stream>>>(sc_out_w, wscout, 393216);
  k_f2b<<<48,   256, 0, stream>>>(sc_xp_w,  wscxp,  49152);

  k_inproj<<<4096, 256, 0, stream>>>(x, in_w, in_b, in_ln_g, in_ln_b, h);

  // ---- 4 main mamba layers ----
  for (int l = 0; l < 4; l++){
    const float* Al = mb_Alog + l*8192;
    k_ln<<<4096, 256, 0, stream>>>(h, mb_ln_g + l*256, mb_ln_b + l*256, xnb, 1024, 0);
    {
      dim3 g(16, 64);
      k_mm64<0><<<g, 256, 0, stream>>>(xnb, wmbin + l*262144, uz,
                                       nullptr, 1, 0, nullptr, 0, 0.f, 4096, 1024, 256);
    }
    k_conv<<<4096, 256, 0, stream>>>(uz, mb_conv_w + l*2048, mb_conv_b + l*512, uc, ucb, 1024);
    {
      dim3 g(1, 64);
      k_mmN<3><<<g, 256, 0, stream>>>(ucb, wmbxp + l*24576, xd, 4096, 512);
    }
    k_dt<<<4096, 256, 0, stream>>>(xd, mb_dt_w + l*8192, mb_dt_b + l*512, dtb_, 48);
    {
      dim3 g(8, 4, NCH);
      k_scan_p1<16><<<g, 64, 0, stream>>>(dtb_, uc, xd, Al, hend, sdtb, 1024, 48, NCH, CL);
      k_scomb<<<128, 256, 0, stream>>>(hend, sdtb, Al, hstart, NCH);
      k_scan_p3<16><<<g, 64, 0, stream>>>(dtb_, uc, uz, xd, Al, mb_D + l*512,
                                          hstart, ygb, 1024, 48, NCH, CL, 0);
    }
    {
      dim3 g(4, 64);
      k_mm64<1><<<g, 256, 0, stream>>>(ygb, wmbout + l*131072, h,
                                       h, 1024, 0, nullptr, 0, 0.f, 4096, 256, 512);
    }
  }

  // ---- scale mambas -> pooled stack ----
  k_zero<<<12, 256, 0, stream>>>(stack, 3072);
  const int scales[3] = {5, 20, 50};
  for (int i = 0; i < 3; i++){
    int s = scales[i];
    int rows = 4*s;
    int mt = (rows + 63)/64;
    k_ln<<<rows, 256, 0, stream>>>(h, sc_ln_g + i*256, sc_ln_b + i*256, xnb, s, 1024 - s);
    {
      dim3 g(16, mt);
      k_mm64<0><<<g, 256, 0, stream>>>(xnb, wscin + i*262144, uz,
                                       nullptr, 1, 0, nullptr, 0, 0.f, rows, 1024, 256);
    }
    k_conv<<<rows, 256, 0, stream>>>(uz, sc_conv_w + i*2048, sc_conv_b + i*512, uc, ucb, s);
    {
      dim3 g(1, mt);
      k_mmN<2><<<g, 256, 0, stream>>>(ucb, wscxp + i*16384, xd, rows, 512);
    }
    k_dt<<<rows, 256, 0, stream>>>(xd, sc_dt_w + i*8192, sc_dt_b + i*512, dtb_, 32);
    {
      dim3 g(8, 4, 1);
      k_scan_p3<8><<<g, 64, 0, stream>>>(dtb_, uc, uz, xd, sc_Alog + i*4096, sc_D + i*512,
                                         nullptr, ygb, s, 32, 1, s, 1);
    }
    {
      dim3 g(4, mt);
      k_mm64<2><<<g, 256, 0, stream>>>(ygb, wscout + i*131072, nullptr,
                                       h, s, 1024 - s, stack, i*256, 1.f/(float)s,
                                       rows, 256, 512);
    }
  }

  // ---- tail (parallel small kernels) ----
  float* dout = (float*)d_out;
  k_tg<12,0,0><<<3, 256, 12*256*4, stream>>>(stack, fus_qkv_w, fus_qkv_b, qkvF, nullptr, 768, 256, 768, 0);
  k_t_att<<<4, 256, 0, stream>>>(qkvF, ovF);
  k_tg<12,0,0><<<1, 256, 12*256*4, stream>>>(ovF, fus_out_w, fus_out_b, moF, nullptr, 256, 256, 256, 0);
  k_tg<4,0,0><<<1, 256, 4*768*4, stream>>>(moF, ms_out_w, ms_out_b, fusedv, nullptr, 256, 768, 256, 0);
  k_t_ln<<<12, 256, 0, stream>>>(stack, sa_ln1_g, sa_ln1_b, lnbuf);
  k_tg<12,0,0><<<3, 256, 12*256*4, stream>>>(lnbuf, sa_qkv_w, sa_qkv_b, qkvS, nullptr, 768, 256, 768, 0);
  k_t_att<<<4, 256, 0, stream>>>(qkvS, ovS);
  k_tg<12,0,1><<<1, 256, 12*256*4, stream>>>(ovS, sa_out_w, sa_out_b, s2, stack, 256, 256, 256, 0);
  k_t_ln<<<12, 256, 0, stream>>>(s2, sa_ln2_g, sa_ln2_b, ln2r);
  k_tg<12,1,0><<<4, 256, 12*256*4, stream>>>(ln2r, sa_ff1_w, sa_ff1_b, hid, nullptr, 1024, 256, 1024, 0);
  k_tg<12,0,1><<<1, 256, 12*1024*4, stream>>>(hid, sa_ff2_w, sa_ff2_b, s2f, s2, 256, 1024, 256, 0);
  k_t_final<<<4, 256, 0, stream>>>(fusedv, s2f, finalv);
  k_tg<4,1,0><<<1, 256, 4*256*4, stream>>>(finalv, ev1_w, ev1_b, evh, nullptr, 256, 256, 256, 0);
  k_tg<4,0,0><<<1, 256, 4*256*4, stream>>>(evh, ev2_w, ev2_b, evraw, nullptr, 7, 256, 7, 0);
  k_tg<4,1,0><<<1, 256, 4*256*4, stream>>>(finalv, ttf1_w, ttf1_b, tth, nullptr, 128, 256, 128, 0);
  k_tg<4,0,0><<<1, 256, 4*128*4, stream>>>(tth, ttf2_w, ttf2_b, ttraw, nullptr, 12, 128, 12, 0);
  k_tg<4,0,0><<<1, 256, 4*256*4, stream>>>(finalv, emb_w, emb_b, dout, nullptr, 128, 256, 162, 34);
  k_t_fin<<<4, 64, 0, stream>>>(evraw, ttraw, dout);
}

// Round 5
// 841.650 us; speedup vs baseline: 4.0422x; 1.3552x over previous
//
#include <hip/hip_runtime.h>
#include <math.h>

// ---------------------------------------------------------------------------
// MambaPredictor forward. R4: wave-per-column tail GEMMs (latency fix).
// B=4 L=1024 NF=64 DM=256 DS=16 SCS=8 NL=4 DI=512 DTR=16 DC=4 NFM=6 NH=4
// ---------------------------------------------------------------------------

typedef short short8v __attribute__((ext_vector_type(8)));
typedef float f32x4   __attribute__((ext_vector_type(4)));

__device__ __forceinline__ float geluf(float x){ return 0.5f*x*(1.0f + erff(x*0.70710678118654752f)); }
__device__ __forceinline__ float softplusf_(float x){ return (x > 20.f) ? x : log1pf(expf(x)); }
__device__ __forceinline__ unsigned short f2bf(float f){
  unsigned int u = __float_as_uint(f);
  unsigned int r = (u + 0x7FFFu + ((u >> 16) & 1u)) >> 16;
  return (unsigned short)r;
}

// ---------------- fp32 -> bf16 bulk convert --------------------------------
__global__ __launch_bounds__(256) void k_f2b(const float* __restrict__ s,
                                             unsigned short* __restrict__ d, int n){
  int i = (blockIdx.x*256 + threadIdx.x)*4;
  if (i < n){
    float4 v = *(const float4*)(s + i);
    *(ushort4*)(d + i) = make_ushort4(f2bf(v.x), f2bf(v.y), f2bf(v.z), f2bf(v.w));
  }
}

// ---------------- initial: h = gelu(LN(x @ in_w^T + in_b)) -----------------
__global__ __launch_bounds__(256) void k_inproj(
    const float* __restrict__ x, const float* __restrict__ w,
    const float* __restrict__ b, const float* __restrict__ g,
    const float* __restrict__ beta, float* __restrict__ h)
{
  __shared__ float xr[64];
  __shared__ float r1[4], r2[4];
  int row = blockIdx.x;
  int tid = threadIdx.x;
  if (tid < 64) xr[tid] = x[row*64 + tid];
  __syncthreads();
  float acc = b[tid];
  const float* wr = w + tid*64;
  #pragma unroll
  for (int k = 0; k < 64; k++) acc += xr[k]*wr[k];
  float s1 = acc, s2 = acc*acc;
  #pragma unroll
  for (int o = 32; o > 0; o >>= 1){ s1 += __shfl_down(s1,o,64); s2 += __shfl_down(s2,o,64); }
  if ((tid & 63) == 0){ r1[tid>>6] = s1; r2[tid>>6] = s2; }
  __syncthreads();
  float S1 = r1[0]+r1[1]+r1[2]+r1[3];
  float S2 = r2[0]+r2[1]+r2[2]+r2[3];
  float m = S1*(1.f/256.f);
  float var = S2*(1.f/256.f) - m*m;
  float xn = (acc - m)*rsqrtf(var + 1e-5f)*g[tid] + beta[tid];
  h[row*256 + tid] = geluf(xn);
}

// ---------------- LayerNorm over 256 -> bf16, gather rows from h -----------
__global__ __launch_bounds__(256) void k_ln(
    const float* __restrict__ src, const float* __restrict__ g, const float* __restrict__ beta,
    unsigned short* __restrict__ dst, int rows_per_b, int src_off)
{
  __shared__ float r1[4], r2[4];
  int r = blockIdx.x, tid = threadIdx.x;
  int b = r / rows_per_b, t = r % rows_per_b;
  float v = src[(b*1024 + src_off + t)*256 + tid];
  float s1 = v, s2 = v*v;
  #pragma unroll
  for (int o = 32; o > 0; o >>= 1){ s1 += __shfl_down(s1,o,64); s2 += __shfl_down(s2,o,64); }
  if ((tid & 63) == 0){ r1[tid>>6] = s1; r2[tid>>6] = s2; }
  __syncthreads();
  float S1 = r1[0]+r1[1]+r1[2]+r1[3];
  float S2 = r2[0]+r2[1]+r2[2]+r2[3];
  float m = S1*(1.f/256.f);
  float var = S2*(1.f/256.f) - m*m;
  dst[r*256 + tid] = f2bf((v - m)*rsqrtf(var + 1e-5f)*g[tid] + beta[tid]);
}

// ---------------- MFMA GEMM: C = A(M,K)bf16 @ W(N,K)bf16^T, fp32 acc -------
template<int MODE>
__global__ __launch_bounds__(256) void k_mm64(
    const unsigned short* __restrict__ A, const unsigned short* __restrict__ W,
    float* __restrict__ C,
    const float* __restrict__ resid, int rows_per_b, int res_off,
    float* __restrict__ pool_out, int pool_off, float pool_scale,
    int M, int N, int K)
{
  int tid = threadIdx.x;
  int wave = tid >> 6, lane = tid & 63;
  int mh = wave & 1, nh = wave >> 1;
  int m0 = blockIdx.y*64 + mh*32;
  int n0 = blockIdx.x*64 + nh*32;
  int lrow = lane & 15, kc = lane >> 4;
  f32x4 acc[2][2] = {{{0.f,0.f,0.f,0.f},{0.f,0.f,0.f,0.f}},{{0.f,0.f,0.f,0.f},{0.f,0.f,0.f,0.f}}};
  for (int k0 = 0; k0 < K; k0 += 32){
    short8v a[2], b[2];
    #pragma unroll
    for (int mi = 0; mi < 2; mi++){
      int r = m0 + mi*16 + lrow; r = min(r, M-1);
      a[mi] = *(const short8v*)(A + r*K + k0 + kc*8);
    }
    #pragma unroll
    for (int ni = 0; ni < 2; ni++){
      int c = n0 + ni*16 + lrow;
      b[ni] = *(const short8v*)(W + c*K + k0 + kc*8);
    }
    #pragma unroll
    for (int mi = 0; mi < 2; mi++)
      #pragma unroll
      for (int ni = 0; ni < 2; ni++)
        acc[mi][ni] = __builtin_amdgcn_mfma_f32_16x16x32_bf16(a[mi], b[ni], acc[mi][ni], 0, 0, 0);
  }
  int rb = kc*4;
  #pragma unroll
  for (int mi = 0; mi < 2; mi++){
    #pragma unroll
    for (int rr = 0; rr < 4; rr++){
      int grow = m0 + mi*16 + rb + rr;
      if (grow >= M) continue;
      int bb = grow / rows_per_b, t = grow % rows_per_b;
      #pragma unroll
      for (int ni = 0; ni < 2; ni++){
        int gcol = n0 + ni*16 + lrow;
        float v = acc[mi][ni][rr];
        if (MODE == 0){
          C[grow*N + gcol] = v;
        } else {
          float rv = resid[(bb*1024 + res_off + t)*256 + gcol] + v;
          if (MODE == 1) C[grow*N + gcol] = rv;
          else atomicAdd(&pool_out[bb*768 + pool_off + gcol], rv*pool_scale);
        }
      }
    }
  }
}

// ---- narrow MFMA GEMM: N = NT*16 (xp proj). One wave per 16-row m-tile ----
template<int NT>
__global__ __launch_bounds__(256) void k_mmN(
    const unsigned short* __restrict__ A, const unsigned short* __restrict__ W,
    float* __restrict__ C, int M, int K)
{
  int tid = threadIdx.x;
  int wave = tid >> 6, lane = tid & 63;
  int m0 = blockIdx.y*64 + wave*16;
  int lrow = lane & 15, kc = lane >> 4;
  f32x4 acc[NT];
  #pragma unroll
  for (int ni = 0; ni < NT; ni++) acc[ni] = (f32x4){0.f,0.f,0.f,0.f};
  for (int k0 = 0; k0 < K; k0 += 32){
    int r = m0 + lrow; r = min(r, M-1);
    short8v a = *(const short8v*)(A + r*K + k0 + kc*8);
    #pragma unroll
    for (int ni = 0; ni < NT; ni++){
      short8v b = *(const short8v*)(W + (ni*16 + lrow)*K + k0 + kc*8);
      acc[ni] = __builtin_amdgcn_mfma_f32_16x16x32_bf16(a, b, acc[ni], 0, 0, 0);
    }
  }
  int rb = kc*4;
  #pragma unroll
  for (int rr = 0; rr < 4; rr++){
    int grow = m0 + rb + rr;
    if (grow >= M) continue;
    #pragma unroll
    for (int ni = 0; ni < NT; ni++)
      C[grow*(NT*16) + ni*16 + lrow] = acc[ni][rr];
  }
}

// ---------------- depthwise causal conv (DC=4) + SiLU ----------------------
__global__ __launch_bounds__(256) void k_conv(
    const float* __restrict__ uz, const float* __restrict__ cw, const float* __restrict__ cb,
    float* __restrict__ uc, unsigned short* __restrict__ ucb, int Lseq)
{
  int row = blockIdx.x;
  int t = row % Lseq;
  int tid = threadIdx.x;
  for (int d = tid; d < 512; d += 256){
    float acc = cb[d];
    const float* w = cw + d*4;
    #pragma unroll
    for (int k = 0; k < 4; k++){
      int ts = t - 3 + k;
      if (ts >= 0) acc += uz[(row - (3-k))*1024 + d]*w[k];
    }
    float s = acc/(1.f + expf(-acc));
    uc[row*512 + d] = s;
    ucb[row*512 + d] = f2bf(s);
  }
}

// ---------------- dt = softplus(xd[:16] @ dtw^T + dtb) ---------------------
__global__ __launch_bounds__(256) void k_dt(
    const float* __restrict__ xd, const float* __restrict__ dtw, const float* __restrict__ dtb,
    float* __restrict__ dt, int xdld)
{
  __shared__ float sx[16];
  int row = blockIdx.x, tid = threadIdx.x;
  if (tid < 16) sx[tid] = xd[row*xdld + tid];
  __syncthreads();
  for (int d = tid; d < 512; d += 256){
    float acc = dtb[d];
    const float* w = dtw + d*16;
    #pragma unroll
    for (int j = 0; j < 16; j++) acc += sx[j]*w[j];
    dt[row*512 + d] = softplusf_(acc);
  }
}

// ============ chunked selective scan (3-pass) ==============================
template<int DS>
__global__ __launch_bounds__(64) void k_scan_p1(
    const float* __restrict__ dt, const float* __restrict__ uc,
    const float* __restrict__ xd, const float* __restrict__ Alog,
    float* __restrict__ hend, float* __restrict__ sdtb,
    int Lseq, int xdld, int NCH, int CL)
{
  const int Q = DS/4;
  __shared__ float sB[64][DS];
  int tid = threadIdx.x;
  int d = blockIdx.x*64 + tid;
  int b = blockIdx.y, ch = blockIdx.z;
  int t0 = ch*CL;
  float A[DS];
  #pragma unroll
  for (int n = 0; n < DS; n++) A[n] = -__expf(Alog[d*DS + n]);
  for (int e = tid; e < CL*Q; e += 64){
    int t = e/Q, q = e%Q;
    *(float4*)&sB[t][q*4] = *(const float4*)(xd + (b*Lseq + t0 + t)*xdld + 16 + q*4);
  }
  __syncthreads();
  float h[DS];
  #pragma unroll
  for (int n = 0; n < DS; n++) h[n] = 0.f;
  float Ssum = 0.f;
  for (int t = 0; t < CL; t++){
    int row = b*Lseq + t0 + t;
    float dtv = dt[row*512 + d];
    float uv  = uc[row*512 + d];
    Ssum += dtv;
    float du = dtv*uv;
    #pragma unroll
    for (int n = 0; n < DS; n++)
      h[n] = fmaf(__expf(dtv*A[n]), h[n], du*sB[t][n]);
  }
  int base = ((b*NCH + ch)*512 + d)*DS;
  #pragma unroll
  for (int q = 0; q < Q; q++)
    *(float4*)(hend + base + q*4) = make_float4(h[q*4], h[q*4+1], h[q*4+2], h[q*4+3]);
  sdtb[(b*NCH + ch)*512 + d] = Ssum;
}

__global__ __launch_bounds__(256) void k_scomb(
    const float* __restrict__ hend, const float* __restrict__ sdtb,
    const float* __restrict__ Alog, float* __restrict__ hstart, int NCH)
{
  int idx = blockIdx.x*256 + threadIdx.x;
  int low = idx & 8191;
  int n = idx & 15, d = (idx >> 4) & 511, b = idx >> 13;
  float A = -__expf(Alog[d*16 + n]);
  float hs = 0.f;
  hstart[(b*NCH)*8192 + low] = 0.f;
  for (int c = 0; c < NCH-1; c++){
    float S  = sdtb[(b*NCH + c)*512 + d];
    float he = hend[(b*NCH + c)*8192 + low];
    hs = fmaf(__expf(A*S), hs, he);
    hstart[(b*NCH + c + 1)*8192 + low] = hs;
  }
}

template<int DS>
__global__ __launch_bounds__(64) void k_scan_p3(
    const float* __restrict__ dt, const float* __restrict__ uc,
    const float* __restrict__ uz, const float* __restrict__ xd,
    const float* __restrict__ Alog, const float* __restrict__ Dp,
    const float* __restrict__ hstart, unsigned short* __restrict__ yg,
    int Lseq, int xdld, int NCH, int CL, int init0)
{
  const int Q2 = DS/2;
  __shared__ float sBC[64][2*DS];
  int tid = threadIdx.x;
  int d = blockIdx.x*64 + tid;
  int b = blockIdx.y, ch = blockIdx.z;
  int t0 = ch*CL;
  float A[DS];
  #pragma unroll
  for (int n = 0; n < DS; n++) A[n] = -__expf(Alog[d*DS + n]);
  float Dv = Dp[d];
  for (int e = tid; e < CL*Q2; e += 64){
    int t = e/Q2, q = e%Q2;
    *(float4*)&sBC[t][q*4] = *(const float4*)(xd + (b*Lseq + t0 + t)*xdld + 16 + q*4);
  }
  __syncthreads();
  float h[DS];
  if (init0){
    #pragma unroll
    for (int n = 0; n < DS; n++) h[n] = 0.f;
  } else {
    int base = ((b*NCH + ch)*512 + d)*DS;
    #pragma unroll
    for (int q = 0; q < DS/4; q++){
      float4 v = *(const float4*)(hstart + base + q*4);
      h[q*4] = v.x; h[q*4+1] = v.y; h[q*4+2] = v.z; h[q*4+3] = v.w;
    }
  }
  for (int t = 0; t < CL; t++){
    int row = b*Lseq + t0 + t;
    float dtv = dt[row*512 + d];
    float uv  = uc[row*512 + d];
    float zv  = uz[row*1024 + 512 + d];
    float du = dtv*uv;
    float y = 0.f;
    #pragma unroll
    for (int n = 0; n < DS; n++){
      h[n] = fmaf(__expf(dtv*A[n]), h[n], du*sBC[t][n]);
      y = fmaf(h[n], sBC[t][DS+n], y);
    }
    y = fmaf(uv, Dv, y);
    float gate = zv/(1.f + __expf(-zv));
    yg[row*512 + d] = f2bf(y*gate);
  }
}

__global__ void k_zero(float* p, int n){
  int i = blockIdx.x*256 + threadIdx.x;
  if (i < n) p[i] = 0.f;
}

// ================== tail kernels ==========================================
// wave-per-column GEMM: out(M,N) = act(A(M,K) @ W(N,K)^T + bias) [+resid]
// lane l covers k = l*4 + 256*i : coalesced W loads, <=4 latency exposures.
template<int M, int ACT, int RES>
__global__ __launch_bounds__(256) void k_tw(
    const float* __restrict__ A, const float* __restrict__ W,
    const float* __restrict__ bias, float* __restrict__ out,
    const float* __restrict__ resid, int N, int K, int ostride, int ocoff)
{
  extern __shared__ float sx[];
  int tid = threadIdx.x;
  for (int e = tid*4; e < M*K; e += 1024)
    *(float4*)&sx[e] = *(const float4*)(A + e);
  __syncthreads();
  int wave = tid >> 6, lane = tid & 63;
  int c = blockIdx.x*4 + wave;
  if (c >= N) return;
  float acc[M];
  #pragma unroll
  for (int r = 0; r < M; r++) acc[r] = 0.f;
  for (int k = lane*4; k < K; k += 256){
    float4 w4 = *(const float4*)(W + c*K + k);
    #pragma unroll
    for (int r = 0; r < M; r++){
      float4 x4 = *(float4*)&sx[r*K + k];
      acc[r] = fmaf(x4.x,w4.x,fmaf(x4.y,w4.y,fmaf(x4.z,w4.z,fmaf(x4.w,w4.w,acc[r]))));
    }
  }
  #pragma unroll
  for (int r = 0; r < M; r++){
    #pragma unroll
    for (int o = 32; o > 0; o >>= 1) acc[r] += __shfl_down(acc[r], o, 64);
  }
  if (lane == 0){
    float bv = bias[c];
    #pragma unroll
    for (int r = 0; r < M; r++){
      float v = acc[r] + bv;
      if (ACT == 1) v = geluf(v);
      if (RES == 1) v += resid[r*256 + c];
      out[r*ostride + ocoff + c] = v;
    }
  }
}

__global__ __launch_bounds__(256) void k_t_ln(
    const float* __restrict__ src, const float* __restrict__ g, const float* __restrict__ b,
    float* __restrict__ dst)
{
  __shared__ float r1[4], r2[4];
  int r = blockIdx.x, tid = threadIdx.x;
  float v = src[r*256 + tid];
  float s1 = v, s2 = v*v;
  #pragma unroll
  for (int o = 32; o > 0; o >>= 1){ s1 += __shfl_down(s1,o,64); s2 += __shfl_down(s2,o,64); }
  if ((tid & 63) == 0){ r1[tid>>6] = s1; r2[tid>>6] = s2; }
  __syncthreads();
  float S1 = r1[0]+r1[1]+r1[2]+r1[3];
  float S2 = r2[0]+r2[1]+r2[2]+r2[3];
  float m = S1*(1.f/256.f);
  float var = S2*(1.f/256.f) - m*m;
  dst[r*256 + tid] = (v - m)*rsqrtf(var + 1e-5f)*g[tid] + b[tid];
}

__global__ __launch_bounds__(256) void k_t_att(
    const float* __restrict__ qkv, float* __restrict__ ov)
{
  __shared__ float att[36];
  int b = blockIdx.x, tid = threadIdx.x;
  if (tid < 36){
    int hh = tid/9, r = (tid%9)/3, c = tid%3;
    float s = 0.f;
    const float* qp = qkv + (b*3 + r)*768 + hh*64;
    const float* kp = qkv + (b*3 + c)*768 + 256 + hh*64;
    for (int k = 0; k < 64; k++) s += qp[k]*kp[k];
    att[hh*9 + r*3 + c] = s*0.125f;
  }
  __syncthreads();
  if (tid < 12){
    int hh = tid/3, r = tid%3;
    float a0 = att[hh*9+r*3+0], a1 = att[hh*9+r*3+1], a2 = att[hh*9+r*3+2];
    float m = fmaxf(a0, fmaxf(a1, a2));
    float e0 = expf(a0-m), e1 = expf(a1-m), e2 = expf(a2-m);
    float s = e0+e1+e2;
    att[hh*9+r*3+0] = e0/s; att[hh*9+r*3+1] = e1/s; att[hh*9+r*3+2] = e2/s;
  }
  __syncthreads();
  for (int e = tid; e < 768; e += 256){
    int p = e >> 8, i = e & 255, hh = i >> 6;
    ov[(b*3 + p)*256 + i] = att[hh*9+p*3+0]*qkv[(b*3+0)*768+512+i]
                          + att[hh*9+p*3+1]*qkv[(b*3+1)*768+512+i]
                          + att[hh*9+p*3+2]*qkv[(b*3+2)*768+512+i];
  }
}

__global__ __launch_bounds__(256) void k_t_final(
    const float* __restrict__ fusedv, const float* __restrict__ s2f, float* __restrict__ finalv)
{
  int b = blockIdx.x, c = threadIdx.x;
  finalv[b*256 + c] = fusedv[b*256 + c] +
    (s2f[(b*3+0)*256 + c] + s2f[(b*3+1)*256 + c] + s2f[(b*3+2)*256 + c])*(1.f/3.f);
}

__global__ __launch_bounds__(64) void k_t_fin(
    const float* __restrict__ evraw, const float* __restrict__ ttraw, float* __restrict__ out)
{
  __shared__ float ev[7];
  __shared__ float S;
  int b = blockIdx.x, tid = threadIdx.x;
  if (tid < 7) ev[tid] = softplusf_(evraw[b*7 + tid]);
  __syncthreads();
  if (tid == 0){
    float s = 0.f;
    for (int j = 0; j < 7; j++) s += ev[j] + 1.f;
    S = s;
  }
  __syncthreads();
  float* ob = out + b*162;
  if (tid < 7){
    float al = ev[tid] + 1.f;
    ob[tid] = al / S;
    ob[7 + tid] = ev[tid];
    ob[14 + tid] = al;
  }
  if (tid == 0) ob[21] = 7.f / S;
  if (tid < 6){
    ob[22 + tid] = softplusf_(ttraw[b*12 + tid]);
    ob[28 + tid] = expf(0.5f*ttraw[b*12 + 6 + tid]);
  }
}

// ---------------------------------------------------------------------------
extern "C" void kernel_launch(void* const* d_in, const int* in_sizes, int n_in,
                              void* d_out, int out_size, void* d_ws, size_t ws_size,
                              hipStream_t stream)
{
  const float* x         = (const float*)d_in[0];
  const float* in_w      = (const float*)d_in[1];
  const float* in_b      = (const float*)d_in[2];
  const float* in_ln_g   = (const float*)d_in[3];
  const float* in_ln_b   = (const float*)d_in[4];
  const float* mb_ln_g   = (const float*)d_in[5];
  const float* mb_ln_b   = (const float*)d_in[6];
  const float* mb_in_w   = (const float*)d_in[7];
  const float* mb_conv_w = (const float*)d_in[8];
  const float* mb_conv_b = (const float*)d_in[9];
  const float* mb_xp_w   = (const float*)d_in[10];
  const float* mb_dt_w   = (const float*)d_in[11];
  const float* mb_dt_b   = (const float*)d_in[12];
  const float* mb_Alog   = (const float*)d_in[13];
  const float* mb_D      = (const float*)d_in[14];
  const float* mb_out_w  = (const float*)d_in[15];
  const float* sc_ln_g   = (const float*)d_in[16];
  const float* sc_ln_b   = (const float*)d_in[17];
  const float* sc_in_w   = (const float*)d_in[18];
  const float* sc_conv_w = (const float*)d_in[19];
  const float* sc_conv_b = (const float*)d_in[20];
  const float* sc_xp_w   = (const float*)d_in[21];
  const float* sc_dt_w   = (const float*)d_in[22];
  const float* sc_dt_b   = (const float*)d_in[23];
  const float* sc_Alog   = (const float*)d_in[24];
  const float* sc_D      = (const float*)d_in[25];
  const float* sc_out_w  = (const float*)d_in[26];
  const float* fus_qkv_w = (const float*)d_in[27];
  const float* fus_qkv_b = (const float*)d_in[28];
  const float* fus_out_w = (const float*)d_in[29];
  const float* fus_out_b = (const float*)d_in[30];
  const float* ms_out_w  = (const float*)d_in[31];
  const float* ms_out_b  = (const float*)d_in[32];
  const float* sa_ln1_g  = (const float*)d_in[33];
  const float* sa_ln1_b  = (const float*)d_in[34];
  const float* sa_ln2_g  = (const float*)d_in[35];
  const float* sa_ln2_b  = (const float*)d_in[36];
  const float* sa_qkv_w  = (const float*)d_in[37];
  const float* sa_qkv_b  = (const float*)d_in[38];
  const float* sa_out_w  = (const float*)d_in[39];
  const float* sa_out_b  = (const float*)d_in[40];
  const float* sa_ff1_w  = (const float*)d_in[41];
  const float* sa_ff1_b  = (const float*)d_in[42];
  const float* sa_ff2_w  = (const float*)d_in[43];
  const float* sa_ff2_b  = (const float*)d_in[44];
  const float* ev1_w     = (const float*)d_in[45];
  const float* ev1_b     = (const float*)d_in[46];
  const float* ev2_w     = (const float*)d_in[47];
  const float* ev2_b     = (const float*)d_in[48];
  const float* ttf1_w    = (const float*)d_in[49];
  const float* ttf1_b    = (const float*)d_in[50];
  const float* ttf2_w    = (const float*)d_in[51];
  const float* ttf2_b    = (const float*)d_in[52];
  const float* emb_w     = (const float*)d_in[53];
  const float* emb_b     = (const float*)d_in[54];

  const int NCH = 16, CL = 64;

  float* ws = (float*)d_ws;
  float* h     = ws;                        // 1,048,576
  float* uz    = h    + 1048576;            // 4,194,304
  float* uc    = uz   + 4194304;            // 2,097,152
  float* dtb_  = uc   + 2097152;            // 2,097,152
  float* xd    = dtb_ + 2097152;            // 196,608
  float* stack = xd   + 196608;             // 4,096
  float* tb    = stack + 4096;
  float* qkvF   = tb;            // 9216
  float* ovF    = qkvF + 9216;   // 3072
  float* moF    = ovF  + 3072;   // 3072
  float* fusedv = moF  + 3072;   // 1024
  float* lnbuf  = fusedv + 1024; // 3072
  float* qkvS   = lnbuf + 3072;  // 9216
  float* ovS    = qkvS + 9216;   // 3072
  float* s2     = ovS  + 3072;   // 3072
  float* ln2r   = s2   + 3072;   // 3072
  float* hid    = ln2r + 3072;   // 12288
  float* s2f    = hid  + 12288;  // 3072
  float* finalv = s2f  + 3072;   // 1024
  float* evh    = finalv + 1024; // 1024
  float* tth    = evh  + 1024;   // 512
  float* evraw  = tth  + 512;    // 32
  float* ttraw  = evraw + 32;    // 64
  float* hend   = ttraw + 64;            // 524,288
  float* hstart = hend + 524288;         // 524,288
  float* sdtb   = hstart + 524288;       // 32,768
  float* fp32_end = sdtb + 32768;
  unsigned short* bfb = (unsigned short*)fp32_end;
  unsigned short* xnb    = bfb;                  // 1,048,576
  unsigned short* ucb    = xnb + 1048576;        // 2,097,152
  unsigned short* ygb    = ucb + 2097152;        // 2,097,152
  unsigned short* wmbin  = ygb + 2097152;        // 1,048,576
  unsigned short* wmbout = wmbin + 1048576;      // 524,288
  unsigned short* wmbxp  = wmbout + 524288;      // 98,304
  unsigned short* wscin  = wmbxp + 98304;        // 786,432
  unsigned short* wscout = wscin + 786432;       // 393,216
  unsigned short* wscxp  = wscout + 393216;      // 49,152

  k_f2b<<<1024, 256, 0, stream>>>(mb_in_w,  wmbin,  1048576);
  k_f2b<<<512,  256, 0, stream>>>(mb_out_w, wmbout, 524288);
  k_f2b<<<96,   256, 0, stream>>>(mb_xp_w,  wmbxp,  98304);
  k_f2b<<<768,  256, 0, stream>>>(sc_in_w,  wscin,  786432);
  k_f2b<<<384,  256, 0, stream>>>(sc_out_w, wscout, 393216);
  k_f2b<<<48,   256, 0, stream>>>(sc_xp_w,  wscxp,  49152);

  k_inproj<<<4096, 256, 0, stream>>>(x, in_w, in_b, in_ln_g, in_ln_b, h);

  for (int l = 0; l < 4; l++){
    const float* Al = mb_Alog + l*8192;
    k_ln<<<4096, 256, 0, stream>>>(h, mb_ln_g + l*256, mb_ln_b + l*256, xnb, 1024, 0);
    {
      dim3 g(16, 64);
      k_mm64<0><<<g, 256, 0, stream>>>(xnb, wmbin + l*262144, uz,
                                       nullptr, 1, 0, nullptr, 0, 0.f, 4096, 1024, 256);
    }
    k_conv<<<4096, 256, 0, stream>>>(uz, mb_conv_w + l*2048, mb_conv_b + l*512, uc, ucb, 1024);
    {
      dim3 g(1, 64);
      k_mmN<3><<<g, 256, 0, stream>>>(ucb, wmbxp + l*24576, xd, 4096, 512);
    }
    k_dt<<<4096, 256, 0, stream>>>(xd, mb_dt_w + l*8192, mb_dt_b + l*512, dtb_, 48);
    {
      dim3 g(8, 4, NCH);
      k_scan_p1<16><<<g, 64, 0, stream>>>(dtb_, uc, xd, Al, hend, sdtb, 1024, 48, NCH, CL);
      k_scomb<<<128, 256, 0, stream>>>(hend, sdtb, Al, hstart, NCH);
      k_scan_p3<16><<<g, 64, 0, stream>>>(dtb_, uc, uz, xd, Al, mb_D + l*512,
                                          hstart, ygb, 1024, 48, NCH, CL, 0);
    }
    {
      dim3 g(4, 64);
      k_mm64<1><<<g, 256, 0, stream>>>(ygb, wmbout + l*131072, h,
                                       h, 1024, 0, nullptr, 0, 0.f, 4096, 256, 512);
    }
  }

  k_zero<<<12, 256, 0, stream>>>(stack, 3072);
  const int scales[3] = {5, 20, 50};
  for (int i = 0; i < 3; i++){
    int s = scales[i];
    int rows = 4*s;
    int mt = (rows + 63)/64;
    k_ln<<<rows, 256, 0, stream>>>(h, sc_ln_g + i*256, sc_ln_b + i*256, xnb, s, 1024 - s);
    {
      dim3 g(16, mt);
      k_mm64<0><<<g, 256, 0, stream>>>(xnb, wscin + i*262144, uz,
                                       nullptr, 1, 0, nullptr, 0, 0.f, rows, 1024, 256);
    }
    k_conv<<<rows, 256, 0, stream>>>(uz, sc_conv_w + i*2048, sc_conv_b + i*512, uc, ucb, s);
    {
      dim3 g(1, mt);
      k_mmN<2><<<g, 256, 0, stream>>>(ucb, wscxp + i*16384, xd, rows, 512);
    }
    k_dt<<<rows, 256, 0, stream>>>(xd, sc_dt_w + i*8192, sc_dt_b + i*512, dtb_, 32);
    {
      dim3 g(8, 4, 1);
      k_scan_p3<8><<<g, 64, 0, stream>>>(dtb_, uc, uz, xd, sc_Alog + i*4096, sc_D + i*512,
                                         nullptr, ygb, s, 32, 1, s, 1);
    }
    {
      dim3 g(4, mt);
      k_mm64<2><<<g, 256, 0, stream>>>(ygb, wscout + i*131072, nullptr,
                                       h, s, 1024 - s, stack, i*256, 1.f/(float)s,
                                       rows, 256, 512);
    }
  }

  // ---- tail (wave-per-column GEMMs) ----
  float* dout = (float*)d_out;
  k_tw<12,0,0><<<192, 256, 12*256*4, stream>>>(stack, fus_qkv_w, fus_qkv_b, qkvF, nullptr, 768, 256, 768, 0);
  k_t_att<<<4, 256, 0, stream>>>(qkvF, ovF);
  k_tw<12,0,0><<<64, 256, 12*256*4, stream>>>(ovF, fus_out_w, fus_out_b, moF, nullptr, 256, 256, 256, 0);
  k_tw<4,0,0><<<64, 256, 4*768*4, stream>>>(moF, ms_out_w, ms_out_b, fusedv, nullptr, 256, 768, 256, 0);
  k_t_ln<<<12, 256, 0, stream>>>(stack, sa_ln1_g, sa_ln1_b, lnbuf);
  k_tw<12,0,0><<<192, 256, 12*256*4, stream>>>(lnbuf, sa_qkv_w, sa_qkv_b, qkvS, nullptr, 768, 256, 768, 0);
  k_t_att<<<4, 256, 0, stream>>>(qkvS, ovS);
  k_tw<12,0,1><<<64, 256, 12*256*4, stream>>>(ovS, sa_out_w, sa_out_b, s2, stack, 256, 256, 256, 0);
  k_t_ln<<<12, 256, 0, stream>>>(s2, sa_ln2_g, sa_ln2_b, ln2r);
  k_tw<12,1,0><<<256, 256, 12*256*4, stream>>>(ln2r, sa_ff1_w, sa_ff1_b, hid, nullptr, 1024, 256, 1024, 0);
  k_tw<12,0,1><<<64, 256, 12*1024*4, stream>>>(hid, sa_ff2_w, sa_ff2_b, s2f, s2, 256, 1024, 256, 0);
  k_t_final<<<4, 256, 0, stream>>>(fusedv, s2f, finalv);
  k_tw<4,1,0><<<64, 256, 4*256*4, stream>>>(finalv, ev1_w, ev1_b, evh, nullptr, 256, 256, 256, 0);
  k_tw<4,0,0><<<2, 256, 4*256*4, stream>>>(evh, ev2_w, ev2_b, evraw, nullptr, 7, 256, 7, 0);
  k_tw<4,1,0><<<32, 256, 4*256*4, stream>>>(finalv, ttf1_w, ttf1_b, tth, nullptr, 128, 256, 128, 0);
  k_tw<4,0,0><<<3, 256, 4*128*4, stream>>>(tth, ttf2_w, ttf2_b, ttraw, nullptr, 12, 128, 12, 0);
  k_tw<4,0,0><<<32, 256, 4*256*4, stream>>>(finalv, emb_w, emb_b, dout, nullptr, 128, 256, 162, 34);
  k_t_fin<<<4, 64, 0, stream>>>(evraw, ttraw, dout);
}

// Round 6
// 743.116 us; speedup vs baseline: 4.5781x; 1.1326x over previous
//
#include <hip/hip_runtime.h>
#include <math.h>

// ---------------------------------------------------------------------------
// MambaPredictor forward. R5: LDS-staged chunked scan (latency off the loop).
// B=4 L=1024 NF=64 DM=256 DS=16 SCS=8 NL=4 DI=512 DTR=16 DC=4 NFM=6 NH=4
// ---------------------------------------------------------------------------

typedef short short8v __attribute__((ext_vector_type(8)));
typedef float f32x4   __attribute__((ext_vector_type(4)));

__device__ __forceinline__ float geluf(float x){ return 0.5f*x*(1.0f + erff(x*0.70710678118654752f)); }
__device__ __forceinline__ float softplusf_(float x){ return (x > 20.f) ? x : log1pf(expf(x)); }
__device__ __forceinline__ unsigned short f2bf(float f){
  unsigned int u = __float_as_uint(f);
  unsigned int r = (u + 0x7FFFu + ((u >> 16) & 1u)) >> 16;
  return (unsigned short)r;
}

// ---------------- fp32 -> bf16 bulk convert --------------------------------
__global__ __launch_bounds__(256) void k_f2b(const float* __restrict__ s,
                                             unsigned short* __restrict__ d, int n){
  int i = (blockIdx.x*256 + threadIdx.x)*4;
  if (i < n){
    float4 v = *(const float4*)(s + i);
    *(ushort4*)(d + i) = make_ushort4(f2bf(v.x), f2bf(v.y), f2bf(v.z), f2bf(v.w));
  }
}

// ---------------- initial: h = gelu(LN(x @ in_w^T + in_b)) -----------------
__global__ __launch_bounds__(256) void k_inproj(
    const float* __restrict__ x, const float* __restrict__ w,
    const float* __restrict__ b, const float* __restrict__ g,
    const float* __restrict__ beta, float* __restrict__ h)
{
  __shared__ float xr[64];
  __shared__ float r1[4], r2[4];
  int row = blockIdx.x;
  int tid = threadIdx.x;
  if (tid < 64) xr[tid] = x[row*64 + tid];
  __syncthreads();
  float acc = b[tid];
  const float* wr = w + tid*64;
  #pragma unroll
  for (int k = 0; k < 64; k++) acc += xr[k]*wr[k];
  float s1 = acc, s2 = acc*acc;
  #pragma unroll
  for (int o = 32; o > 0; o >>= 1){ s1 += __shfl_down(s1,o,64); s2 += __shfl_down(s2,o,64); }
  if ((tid & 63) == 0){ r1[tid>>6] = s1; r2[tid>>6] = s2; }
  __syncthreads();
  float S1 = r1[0]+r1[1]+r1[2]+r1[3];
  float S2 = r2[0]+r2[1]+r2[2]+r2[3];
  float m = S1*(1.f/256.f);
  float var = S2*(1.f/256.f) - m*m;
  float xn = (acc - m)*rsqrtf(var + 1e-5f)*g[tid] + beta[tid];
  h[row*256 + tid] = geluf(xn);
}

// ---------------- LayerNorm over 256 -> bf16, gather rows from h -----------
__global__ __launch_bounds__(256) void k_ln(
    const float* __restrict__ src, const float* __restrict__ g, const float* __restrict__ beta,
    unsigned short* __restrict__ dst, int rows_per_b, int src_off)
{
  __shared__ float r1[4], r2[4];
  int r = blockIdx.x, tid = threadIdx.x;
  int b = r / rows_per_b, t = r % rows_per_b;
  float v = src[(b*1024 + src_off + t)*256 + tid];
  float s1 = v, s2 = v*v;
  #pragma unroll
  for (int o = 32; o > 0; o >>= 1){ s1 += __shfl_down(s1,o,64); s2 += __shfl_down(s2,o,64); }
  if ((tid & 63) == 0){ r1[tid>>6] = s1; r2[tid>>6] = s2; }
  __syncthreads();
  float S1 = r1[0]+r1[1]+r1[2]+r1[3];
  float S2 = r2[0]+r2[1]+r2[2]+r2[3];
  float m = S1*(1.f/256.f);
  float var = S2*(1.f/256.f) - m*m;
  dst[r*256 + tid] = f2bf((v - m)*rsqrtf(var + 1e-5f)*g[tid] + beta[tid]);
}

// ---------------- MFMA GEMM: C = A(M,K)bf16 @ W(N,K)bf16^T, fp32 acc -------
template<int MODE>
__global__ __launch_bounds__(256) void k_mm64(
    const unsigned short* __restrict__ A, const unsigned short* __restrict__ W,
    float* __restrict__ C,
    const float* __restrict__ resid, int rows_per_b, int res_off,
    float* __restrict__ pool_out, int pool_off, float pool_scale,
    int M, int N, int K)
{
  int tid = threadIdx.x;
  int wave = tid >> 6, lane = tid & 63;
  int mh = wave & 1, nh = wave >> 1;
  int m0 = blockIdx.y*64 + mh*32;
  int n0 = blockIdx.x*64 + nh*32;
  int lrow = lane & 15, kc = lane >> 4;
  f32x4 acc[2][2] = {{{0.f,0.f,0.f,0.f},{0.f,0.f,0.f,0.f}},{{0.f,0.f,0.f,0.f},{0.f,0.f,0.f,0.f}}};
  for (int k0 = 0; k0 < K; k0 += 32){
    short8v a[2], b[2];
    #pragma unroll
    for (int mi = 0; mi < 2; mi++){
      int r = m0 + mi*16 + lrow; r = min(r, M-1);
      a[mi] = *(const short8v*)(A + r*K + k0 + kc*8);
    }
    #pragma unroll
    for (int ni = 0; ni < 2; ni++){
      int c = n0 + ni*16 + lrow;
      b[ni] = *(const short8v*)(W + c*K + k0 + kc*8);
    }
    #pragma unroll
    for (int mi = 0; mi < 2; mi++)
      #pragma unroll
      for (int ni = 0; ni < 2; ni++)
        acc[mi][ni] = __builtin_amdgcn_mfma_f32_16x16x32_bf16(a[mi], b[ni], acc[mi][ni], 0, 0, 0);
  }
  int rb = kc*4;
  #pragma unroll
  for (int mi = 0; mi < 2; mi++){
    #pragma unroll
    for (int rr = 0; rr < 4; rr++){
      int grow = m0 + mi*16 + rb + rr;
      if (grow >= M) continue;
      int bb = grow / rows_per_b, t = grow % rows_per_b;
      #pragma unroll
      for (int ni = 0; ni < 2; ni++){
        int gcol = n0 + ni*16 + lrow;
        float v = acc[mi][ni][rr];
        if (MODE == 0){
          C[grow*N + gcol] = v;
        } else {
          float rv = resid[(bb*1024 + res_off + t)*256 + gcol] + v;
          if (MODE == 1) C[grow*N + gcol] = rv;
          else atomicAdd(&pool_out[bb*768 + pool_off + gcol], rv*pool_scale);
        }
      }
    }
  }
}

// ---- narrow MFMA GEMM: N = NT*16 (xp proj). One wave per 16-row m-tile ----
template<int NT>
__global__ __launch_bounds__(256) void k_mmN(
    const unsigned short* __restrict__ A, const unsigned short* __restrict__ W,
    float* __restrict__ C, int M, int K)
{
  int tid = threadIdx.x;
  int wave = tid >> 6, lane = tid & 63;
  int m0 = blockIdx.y*64 + wave*16;
  int lrow = lane & 15, kc = lane >> 4;
  f32x4 acc[NT];
  #pragma unroll
  for (int ni = 0; ni < NT; ni++) acc[ni] = (f32x4){0.f,0.f,0.f,0.f};
  for (int k0 = 0; k0 < K; k0 += 32){
    int r = m0 + lrow; r = min(r, M-1);
    short8v a = *(const short8v*)(A + r*K + k0 + kc*8);
    #pragma unroll
    for (int ni = 0; ni < NT; ni++){
      short8v b = *(const short8v*)(W + (ni*16 + lrow)*K + k0 + kc*8);
      acc[ni] = __builtin_amdgcn_mfma_f32_16x16x32_bf16(a, b, acc[ni], 0, 0, 0);
    }
  }
  int rb = kc*4;
  #pragma unroll
  for (int rr = 0; rr < 4; rr++){
    int grow = m0 + rb + rr;
    if (grow >= M) continue;
    #pragma unroll
    for (int ni = 0; ni < NT; ni++)
      C[grow*(NT*16) + ni*16 + lrow] = acc[ni][rr];
  }
}

// ---------------- depthwise causal conv (DC=4) + SiLU ----------------------
__global__ __launch_bounds__(256) void k_conv(
    const float* __restrict__ uz, const float* __restrict__ cw, const float* __restrict__ cb,
    float* __restrict__ uc, unsigned short* __restrict__ ucb, int Lseq)
{
  int row = blockIdx.x;
  int t = row % Lseq;
  int tid = threadIdx.x;
  for (int d = tid; d < 512; d += 256){
    float acc = cb[d];
    const float* w = cw + d*4;
    #pragma unroll
    for (int k = 0; k < 4; k++){
      int ts = t - 3 + k;
      if (ts >= 0) acc += uz[(row - (3-k))*1024 + d]*w[k];
    }
    float s = acc/(1.f + expf(-acc));
    uc[row*512 + d] = s;
    ucb[row*512 + d] = f2bf(s);
  }
}

// ---------------- dt = softplus(xd[:16] @ dtw^T + dtb) ---------------------
__global__ __launch_bounds__(256) void k_dt(
    const float* __restrict__ xd, const float* __restrict__ dtw, const float* __restrict__ dtb,
    float* __restrict__ dt, int xdld)
{
  __shared__ float sx[16];
  int row = blockIdx.x, tid = threadIdx.x;
  if (tid < 16) sx[tid] = xd[row*xdld + tid];
  __syncthreads();
  for (int d = tid; d < 512; d += 256){
    float acc = dtb[d];
    const float* w = dtw + d*16;
    #pragma unroll
    for (int j = 0; j < 16; j++) acc += sx[j]*w[j];
    dt[row*512 + d] = softplusf_(acc);
  }
}

// ============ chunked selective scan (3-pass), LDS-staged ==================
// block = 64 threads = one wave; thread owns one d-channel, DS states in reg.
// All per-t inputs staged to LDS up-front (coalesced float4), so the serial
// t-loop touches only LDS + VALU.

// pass 1: local scan (h0=0) -> hend, sum(dt) -> sdtb
template<int DS>
__global__ __launch_bounds__(64) void k_scan_p1(
    const float* __restrict__ dt, const float* __restrict__ uc,
    const float* __restrict__ xd, const float* __restrict__ Alog,
    float* __restrict__ hend, float* __restrict__ sdtb,
    int Lseq, int xdld, int NCH, int CL)
{
  const int Q = DS/4;
  __shared__ float sdt[64][64], suc[64][64];
  __shared__ float sB[64][DS];
  int tid = threadIdx.x;
  int dblk = blockIdx.x;
  int d = dblk*64 + tid;
  int b = blockIdx.y, ch = blockIdx.z;
  int t0 = ch*CL;
  float A[DS];
  #pragma unroll
  for (int n = 0; n < DS; n++) A[n] = -__expf(Alog[d*DS + n]);
  // stage dt & uc: [CL][64] each, float4-coalesced
  for (int e = tid; e < CL*16; e += 64){
    int t = e >> 4, q = (e & 15)*4;
    long off = (long)(b*Lseq + t0 + t)*512 + dblk*64 + q;
    *(float4*)&sdt[t][q] = *(const float4*)(dt + off);
    *(float4*)&suc[t][q] = *(const float4*)(uc + off);
  }
  for (int e = tid; e < CL*Q; e += 64){
    int t = e/Q, q = (e%Q)*4;
    *(float4*)&sB[t][q] = *(const float4*)(xd + (long)(b*Lseq + t0 + t)*xdld + 16 + q);
  }
  __syncthreads();
  float h[DS];
  #pragma unroll
  for (int n = 0; n < DS; n++) h[n] = 0.f;
  float Ssum = 0.f;
  #pragma unroll 2
  for (int t = 0; t < CL; t++){
    float dtv = sdt[t][tid];
    float uv  = suc[t][tid];
    Ssum += dtv;
    float du = dtv*uv;
    #pragma unroll
    for (int n = 0; n < DS; n++)
      h[n] = fmaf(__expf(dtv*A[n]), h[n], du*sB[t][n]);
  }
  int base = ((b*NCH + ch)*512 + d)*DS;
  #pragma unroll
  for (int q = 0; q < Q; q++)
    *(float4*)(hend + base + q*4) = make_float4(h[q*4], h[q*4+1], h[q*4+2], h[q*4+3]);
  sdtb[(b*NCH + ch)*512 + d] = Ssum;
}

// pass 2: sequential combine over chunks; one thread per (b,d,n). DS=16 only.
__global__ __launch_bounds__(256) void k_scomb(
    const float* __restrict__ hend, const float* __restrict__ sdtb,
    const float* __restrict__ Alog, float* __restrict__ hstart, int NCH)
{
  int idx = blockIdx.x*256 + threadIdx.x;
  int low = idx & 8191;
  int n = idx & 15, d = (idx >> 4) & 511, b = idx >> 13;
  float A = -__expf(Alog[d*16 + n]);
  float hs = 0.f;
  hstart[(b*NCH)*8192 + low] = 0.f;
  for (int c = 0; c < NCH-1; c++){
    float S  = sdtb[(b*NCH + c)*512 + d];
    float he = hend[(b*NCH + c)*8192 + low];
    hs = fmaf(__expf(A*S), hs, he);
    hstart[(b*NCH + c + 1)*8192 + low] = hs;
  }
}

// pass 3: re-scan from true start state; fused C-dot + D-skip + SiLU gate.
template<int DS>
__global__ __launch_bounds__(64) void k_scan_p3(
    const float* __restrict__ dt, const float* __restrict__ uc,
    const float* __restrict__ uz, const float* __restrict__ xd,
    const float* __restrict__ Alog, const float* __restrict__ Dp,
    const float* __restrict__ hstart, unsigned short* __restrict__ yg,
    int Lseq, int xdld, int NCH, int CL, int init0)
{
  const int Q2 = DS/2;
  __shared__ float sdt[64][64], suc[64][64], sz[64][64];
  __shared__ float sBC[64][2*DS];
  int tid = threadIdx.x;
  int dblk = blockIdx.x;
  int d = dblk*64 + tid;
  int b = blockIdx.y, ch = blockIdx.z;
  int t0 = ch*CL;
  float A[DS];
  #pragma unroll
  for (int n = 0; n < DS; n++) A[n] = -__expf(Alog[d*DS + n]);
  float Dv = Dp[d];
  for (int e = tid; e < CL*16; e += 64){
    int t = e >> 4, q = (e & 15)*4;
    long off = (long)(b*Lseq + t0 + t)*512 + dblk*64 + q;
    *(float4*)&sdt[t][q] = *(const float4*)(dt + off);
    *(float4*)&suc[t][q] = *(const float4*)(uc + off);
    *(float4*)&sz[t][q]  = *(const float4*)(uz + (long)(b*Lseq + t0 + t)*1024 + 512 + dblk*64 + q);
  }
  for (int e = tid; e < CL*Q2; e += 64){
    int t = e/Q2, q = (e%Q2)*4;
    *(float4*)&sBC[t][q] = *(const float4*)(xd + (long)(b*Lseq + t0 + t)*xdld + 16 + q);
  }
  __syncthreads();
  float h[DS];
  if (init0){
    #pragma unroll
    for (int n = 0; n < DS; n++) h[n] = 0.f;
  } else {
    int base = ((b*NCH + ch)*512 + d)*DS;
    #pragma unroll
    for (int q = 0; q < DS/4; q++){
      float4 v = *(const float4*)(hstart + base + q*4);
      h[q*4] = v.x; h[q*4+1] = v.y; h[q*4+2] = v.z; h[q*4+3] = v.w;
    }
  }
  #pragma unroll 2
  for (int t = 0; t < CL; t++){
    float dtv = sdt[t][tid];
    float uv  = suc[t][tid];
    float zv  = sz[t][tid];
    float du = dtv*uv;
    float y = 0.f;
    #pragma unroll
    for (int n = 0; n < DS; n++){
      h[n] = fmaf(__expf(dtv*A[n]), h[n], du*sBC[t][n]);
      y = fmaf(h[n], sBC[t][DS+n], y);
    }
    y = fmaf(uv, Dv, y);
    float gate = zv/(1.f + __expf(-zv));
    yg[(long)(b*Lseq + t0 + t)*512 + d] = f2bf(y*gate);
  }
}

__global__ void k_zero(float* p, int n){
  int i = blockIdx.x*256 + threadIdx.x;
  if (i < n) p[i] = 0.f;
}

// ================== tail kernels ==========================================
template<int M, int ACT, int RES>
__global__ __launch_bounds__(256) void k_tw(
    const float* __restrict__ A, const float* __restrict__ W,
    const float* __restrict__ bias, float* __restrict__ out,
    const float* __restrict__ resid, int N, int K, int ostride, int ocoff)
{
  extern __shared__ float sx[];
  int tid = threadIdx.x;
  for (int e = tid*4; e < M*K; e += 1024)
    *(float4*)&sx[e] = *(const float4*)(A + e);
  __syncthreads();
  int wave = tid >> 6, lane = tid & 63;
  int c = blockIdx.x*4 + wave;
  if (c >= N) return;
  float acc[M];
  #pragma unroll
  for (int r = 0; r < M; r++) acc[r] = 0.f;
  for (int k = lane*4; k < K; k += 256){
    float4 w4 = *(const float4*)(W + c*K + k);
    #pragma unroll
    for (int r = 0; r < M; r++){
      float4 x4 = *(float4*)&sx[r*K + k];
      acc[r] = fmaf(x4.x,w4.x,fmaf(x4.y,w4.y,fmaf(x4.z,w4.z,fmaf(x4.w,w4.w,acc[r]))));
    }
  }
  #pragma unroll
  for (int r = 0; r < M; r++){
    #pragma unroll
    for (int o = 32; o > 0; o >>= 1) acc[r] += __shfl_down(acc[r], o, 64);
  }
  if (lane == 0){
    float bv = bias[c];
    #pragma unroll
    for (int r = 0; r < M; r++){
      float v = acc[r] + bv;
      if (ACT == 1) v = geluf(v);
      if (RES == 1) v += resid[r*256 + c];
      out[r*ostride + ocoff + c] = v;
    }
  }
}

__global__ __launch_bounds__(256) void k_t_ln(
    const float* __restrict__ src, const float* __restrict__ g, const float* __restrict__ b,
    float* __restrict__ dst)
{
  __shared__ float r1[4], r2[4];
  int r = blockIdx.x, tid = threadIdx.x;
  float v = src[r*256 + tid];
  float s1 = v, s2 = v*v;
  #pragma unroll
  for (int o = 32; o > 0; o >>= 1){ s1 += __shfl_down(s1,o,64); s2 += __shfl_down(s2,o,64); }
  if ((tid & 63) == 0){ r1[tid>>6] = s1; r2[tid>>6] = s2; }
  __syncthreads();
  float S1 = r1[0]+r1[1]+r1[2]+r1[3];
  float S2 = r2[0]+r2[1]+r2[2]+r2[3];
  float m = S1*(1.f/256.f);
  float var = S2*(1.f/256.f) - m*m;
  dst[r*256 + tid] = (v - m)*rsqrtf(var + 1e-5f)*g[tid] + b[tid];
}

__global__ __launch_bounds__(256) void k_t_att(
    const float* __restrict__ qkv, float* __restrict__ ov)
{
  __shared__ float att[36];
  int b = blockIdx.x, tid = threadIdx.x;
  if (tid < 36){
    int hh = tid/9, r = (tid%9)/3, c = tid%3;
    float s = 0.f;
    const float* qp = qkv + (b*3 + r)*768 + hh*64;
    const float* kp = qkv + (b*3 + c)*768 + 256 + hh*64;
    for (int k = 0; k < 64; k++) s += qp[k]*kp[k];
    att[hh*9 + r*3 + c] = s*0.125f;
  }
  __syncthreads();
  if (tid < 12){
    int hh = tid/3, r = tid%3;
    float a0 = att[hh*9+r*3+0], a1 = att[hh*9+r*3+1], a2 = att[hh*9+r*3+2];
    float m = fmaxf(a0, fmaxf(a1, a2));
    float e0 = expf(a0-m), e1 = expf(a1-m), e2 = expf(a2-m);
    float s = e0+e1+e2;
    att[hh*9+r*3+0] = e0/s; att[hh*9+r*3+1] = e1/s; att[hh*9+r*3+2] = e2/s;
  }
  __syncthreads();
  for (int e = tid; e < 768; e += 256){
    int p = e >> 8, i = e & 255, hh = i >> 6;
    ov[(b*3 + p)*256 + i] = att[hh*9+p*3+0]*qkv[(b*3+0)*768+512+i]
                          + att[hh*9+p*3+1]*qkv[(b*3+1)*768+512+i]
                          + att[hh*9+p*3+2]*qkv[(b*3+2)*768+512+i];
  }
}

__global__ __launch_bounds__(256) void k_t_final(
    const float* __restrict__ fusedv, const float* __restrict__ s2f, float* __restrict__ finalv)
{
  int b = blockIdx.x, c = threadIdx.x;
  finalv[b*256 + c] = fusedv[b*256 + c] +
    (s2f[(b*3+0)*256 + c] + s2f[(b*3+1)*256 + c] + s2f[(b*3+2)*256 + c])*(1.f/3.f);
}

__global__ __launch_bounds__(64) void k_t_fin(
    const float* __restrict__ evraw, const float* __restrict__ ttraw, float* __restrict__ out)
{
  __shared__ float ev[7];
  __shared__ float S;
  int b = blockIdx.x, tid = threadIdx.x;
  if (tid < 7) ev[tid] = softplusf_(evraw[b*7 + tid]);
  __syncthreads();
  if (tid == 0){
    float s = 0.f;
    for (int j = 0; j < 7; j++) s += ev[j] + 1.f;
    S = s;
  }
  __syncthreads();
  float* ob = out + b*162;
  if (tid < 7){
    float al = ev[tid] + 1.f;
    ob[tid] = al / S;
    ob[7 + tid] = ev[tid];
    ob[14 + tid] = al;
  }
  if (tid == 0) ob[21] = 7.f / S;
  if (tid < 6){
    ob[22 + tid] = softplusf_(ttraw[b*12 + tid]);
    ob[28 + tid] = expf(0.5f*ttraw[b*12 + 6 + tid]);
  }
}

// ---------------------------------------------------------------------------
extern "C" void kernel_launch(void* const* d_in, const int* in_sizes, int n_in,
                              void* d_out, int out_size, void* d_ws, size_t ws_size,
                              hipStream_t stream)
{
  const float* x         = (const float*)d_in[0];
  const float* in_w      = (const float*)d_in[1];
  const float* in_b      = (const float*)d_in[2];
  const float* in_ln_g   = (const float*)d_in[3];
  const float* in_ln_b   = (const float*)d_in[4];
  const float* mb_ln_g   = (const float*)d_in[5];
  const float* mb_ln_b   = (const float*)d_in[6];
  const float* mb_in_w   = (const float*)d_in[7];
  const float* mb_conv_w = (const float*)d_in[8];
  const float* mb_conv_b = (const float*)d_in[9];
  const float* mb_xp_w   = (const float*)d_in[10];
  const float* mb_dt_w   = (const float*)d_in[11];
  const float* mb_dt_b   = (const float*)d_in[12];
  const float* mb_Alog   = (const float*)d_in[13];
  const float* mb_D      = (const float*)d_in[14];
  const float* mb_out_w  = (const float*)d_in[15];
  const float* sc_ln_g   = (const float*)d_in[16];
  const float* sc_ln_b   = (const float*)d_in[17];
  const float* sc_in_w   = (const float*)d_in[18];
  const float* sc_conv_w = (const float*)d_in[19];
  const float* sc_conv_b = (const float*)d_in[20];
  const float* sc_xp_w   = (const float*)d_in[21];
  const float* sc_dt_w   = (const float*)d_in[22];
  const float* sc_dt_b   = (const float*)d_in[23];
  const float* sc_Alog   = (const float*)d_in[24];
  const float* sc_D      = (const float*)d_in[25];
  const float* sc_out_w  = (const float*)d_in[26];
  const float* fus_qkv_w = (const float*)d_in[27];
  const float* fus_qkv_b = (const float*)d_in[28];
  const float* fus_out_w = (const float*)d_in[29];
  const float* fus_out_b = (const float*)d_in[30];
  const float* ms_out_w  = (const float*)d_in[31];
  const float* ms_out_b  = (const float*)d_in[32];
  const float* sa_ln1_g  = (const float*)d_in[33];
  const float* sa_ln1_b  = (const float*)d_in[34];
  const float* sa_ln2_g  = (const float*)d_in[35];
  const float* sa_ln2_b  = (const float*)d_in[36];
  const float* sa_qkv_w  = (const float*)d_in[37];
  const float* sa_qkv_b  = (const float*)d_in[38];
  const float* sa_out_w  = (const float*)d_in[39];
  const float* sa_out_b  = (const float*)d_in[40];
  const float* sa_ff1_w  = (const float*)d_in[41];
  const float* sa_ff1_b  = (const float*)d_in[42];
  const float* sa_ff2_w  = (const float*)d_in[43];
  const float* sa_ff2_b  = (const float*)d_in[44];
  const float* ev1_w     = (const float*)d_in[45];
  const float* ev1_b     = (const float*)d_in[46];
  const float* ev2_w     = (const float*)d_in[47];
  const float* ev2_b     = (const float*)d_in[48];
  const float* ttf1_w    = (const float*)d_in[49];
  const float* ttf1_b    = (const float*)d_in[50];
  const float* ttf2_w    = (const float*)d_in[51];
  const float* ttf2_b    = (const float*)d_in[52];
  const float* emb_w     = (const float*)d_in[53];
  const float* emb_b     = (const float*)d_in[54];

  const int NCH = 16, CL = 64;

  float* ws = (float*)d_ws;
  float* h     = ws;                        // 1,048,576
  float* uz    = h    + 1048576;            // 4,194,304
  float* uc    = uz   + 4194304;            // 2,097,152
  float* dtb_  = uc   + 2097152;            // 2,097,152
  float* xd    = dtb_ + 2097152;            // 196,608
  float* stack = xd   + 196608;             // 4,096
  float* tb    = stack + 4096;
  float* qkvF   = tb;            // 9216
  float* ovF    = qkvF + 9216;   // 3072
  float* moF    = ovF  + 3072;   // 3072
  float* fusedv = moF  + 3072;   // 1024
  float* lnbuf  = fusedv + 1024; // 3072
  float* qkvS   = lnbuf + 3072;  // 9216
  float* ovS    = qkvS + 9216;   // 3072
  float* s2     = ovS  + 3072;   // 3072
  float* ln2r   = s2   + 3072;   // 3072
  float* hid    = ln2r + 3072;   // 12288
  float* s2f    = hid  + 12288;  // 3072
  float* finalv = s2f  + 3072;   // 1024
  float* evh    = finalv + 1024; // 1024
  float* tth    = evh  + 1024;   // 512
  float* evraw  = tth  + 512;    // 32
  float* ttraw  = evraw + 32;    // 64
  float* hend   = ttraw + 64;            // 524,288
  float* hstart = hend + 524288;         // 524,288
  float* sdtb   = hstart + 524288;       // 32,768
  float* fp32_end = sdtb + 32768;
  unsigned short* bfb = (unsigned short*)fp32_end;
  unsigned short* xnb    = bfb;                  // 1,048,576
  unsigned short* ucb    = xnb + 1048576;        // 2,097,152
  unsigned short* ygb    = ucb + 2097152;        // 2,097,152
  unsigned short* wmbin  = ygb + 2097152;        // 1,048,576
  unsigned short* wmbout = wmbin + 1048576;      // 524,288
  unsigned short* wmbxp  = wmbout + 524288;      // 98,304
  unsigned short* wscin  = wmbxp + 98304;        // 786,432
  unsigned short* wscout = wscin + 786432;       // 393,216
  unsigned short* wscxp  = wscout + 393216;      // 49,152

  k_f2b<<<1024, 256, 0, stream>>>(mb_in_w,  wmbin,  1048576);
  k_f2b<<<512,  256, 0, stream>>>(mb_out_w, wmbout, 524288);
  k_f2b<<<96,   256, 0, stream>>>(mb_xp_w,  wmbxp,  98304);
  k_f2b<<<768,  256, 0, stream>>>(sc_in_w,  wscin,  786432);
  k_f2b<<<384,  256, 0, stream>>>(sc_out_w, wscout, 393216);
  k_f2b<<<48,   256, 0, stream>>>(sc_xp_w,  wscxp,  49152);

  k_inproj<<<4096, 256, 0, stream>>>(x, in_w, in_b, in_ln_g, in_ln_b, h);

  for (int l = 0; l < 4; l++){
    const float* Al = mb_Alog + l*8192;
    k_ln<<<4096, 256, 0, stream>>>(h, mb_ln_g + l*256, mb_ln_b + l*256, xnb, 1024, 0);
    {
      dim3 g(16, 64);
      k_mm64<0><<<g, 256, 0, stream>>>(xnb, wmbin + l*262144, uz,
                                       nullptr, 1, 0, nullptr, 0, 0.f, 4096, 1024, 256);
    }
    k_conv<<<4096, 256, 0, stream>>>(uz, mb_conv_w + l*2048, mb_conv_b + l*512, uc, ucb, 1024);
    {
      dim3 g(1, 64);
      k_mmN<3><<<g, 256, 0, stream>>>(ucb, wmbxp + l*24576, xd, 4096, 512);
    }
    k_dt<<<4096, 256, 0, stream>>>(xd, mb_dt_w + l*8192, mb_dt_b + l*512, dtb_, 48);
    {
      dim3 g(8, 4, NCH);
      k_scan_p1<16><<<g, 64, 0, stream>>>(dtb_, uc, xd, Al, hend, sdtb, 1024, 48, NCH, CL);
      k_scomb<<<128, 256, 0, stream>>>(hend, sdtb, Al, hstart, NCH);
      k_scan_p3<16><<<g, 64, 0, stream>>>(dtb_, uc, uz, xd, Al, mb_D + l*512,
                                          hstart, ygb, 1024, 48, NCH, CL, 0);
    }
    {
      dim3 g(4, 64);
      k_mm64<1><<<g, 256, 0, stream>>>(ygb, wmbout + l*131072, h,
                                       h, 1024, 0, nullptr, 0, 0.f, 4096, 256, 512);
    }
  }

  k_zero<<<12, 256, 0, stream>>>(stack, 3072);
  const int scales[3] = {5, 20, 50};
  for (int i = 0; i < 3; i++){
    int s = scales[i];
    int rows = 4*s;
    int mt = (rows + 63)/64;
    k_ln<<<rows, 256, 0, stream>>>(h, sc_ln_g + i*256, sc_ln_b + i*256, xnb, s, 1024 - s);
    {
      dim3 g(16, mt);
      k_mm64<0><<<g, 256, 0, stream>>>(xnb, wscin + i*262144, uz,
                                       nullptr, 1, 0, nullptr, 0, 0.f, rows, 1024, 256);
    }
    k_conv<<<rows, 256, 0, stream>>>(uz, sc_conv_w + i*2048, sc_conv_b + i*512, uc, ucb, s);
    {
      dim3 g(1, mt);
      k_mmN<2><<<g, 256, 0, stream>>>(ucb, wscxp + i*16384, xd, rows, 512);
    }
    k_dt<<<rows, 256, 0, stream>>>(xd, sc_dt_w + i*8192, sc_dt_b + i*512, dtb_, 32);
    {
      dim3 g(8, 4, 1);
      k_scan_p3<8><<<g, 64, 0, stream>>>(dtb_, uc, uz, xd, sc_Alog + i*4096, sc_D + i*512,
                                         nullptr, ygb, s, 32, 1, s, 1);
    }
    {
      dim3 g(4, mt);
      k_mm64<2><<<g, 256, 0, stream>>>(ygb, wscout + i*131072, nullptr,
                                       h, s, 1024 - s, stack, i*256, 1.f/(float)s,
                                       rows, 256, 512);
    }
  }

  // ---- tail (wave-per-column GEMMs) ----
  float* dout = (float*)d_out;
  k_tw<12,0,0><<<192, 256, 12*256*4, stream>>>(stack, fus_qkv_w, fus_qkv_b, qkvF, nullptr, 768, 256, 768, 0);
  k_t_att<<<4, 256, 0, stream>>>(qkvF, ovF);
  k_tw<12,0,0><<<64, 256, 12*256*4, stream>>>(ovF, fus_out_w, fus_out_b, moF, nullptr, 256, 256, 256, 0);
  k_tw<4,0,0><<<64, 256, 4*768*4, stream>>>(moF, ms_out_w, ms_out_b, fusedv, nullptr, 256, 768, 256, 0);
  k_t_ln<<<12, 256, 0, stream>>>(stack, sa_ln1_g, sa_ln1_b, lnbuf);
  k_tw<12,0,0><<<192, 256, 12*256*4, stream>>>(lnbuf, sa_qkv_w, sa_qkv_b, qkvS, nullptr, 768, 256, 768, 0);
  k_t_att<<<4, 256, 0, stream>>>(qkvS, ovS);
  k_tw<12,0,1><<<64, 256, 12*256*4, stream>>>(ovS, sa_out_w, sa_out_b, s2, stack, 256, 256, 256, 0);
  k_t_ln<<<12, 256, 0, stream>>>(s2, sa_ln2_g, sa_ln2_b, ln2r);
  k_tw<12,1,0><<<256, 256, 12*256*4, stream>>>(ln2r, sa_ff1_w, sa_ff1_b, hid, nullptr, 1024, 256, 1024, 0);
  k_tw<12,0,1><<<64, 256, 12*1024*4, stream>>>(hid, sa_ff2_w, sa_ff2_b, s2f, s2, 256, 1024, 256, 0);
  k_t_final<<<4, 256, 0, stream>>>(fusedv, s2f, finalv);
  k_tw<4,1,0><<<64, 256, 4*256*4, stream>>>(finalv, ev1_w, ev1_b, evh, nullptr, 256, 256, 256, 0);
  k_tw<4,0,0><<<2, 256, 4*256*4, stream>>>(evh, ev2_w, ev2_b, evraw, nullptr, 7, 256, 7, 0);
  k_tw<4,1,0><<<32, 256, 4*256*4, stream>>>(finalv, ttf1_w, ttf1_b, tth, nullptr, 128, 256, 128, 0);
  k_tw<4,0,0><<<3, 256, 4*128*4, stream>>>(tth, ttf2_w, ttf2_b, ttraw, nullptr, 12, 128, 12, 0);
  k_tw<4,0,0><<<32, 256, 4*256*4, stream>>>(finalv, emb_w, emb_b, dout, nullptr, 128, 256, 162, 34);
  k_t_fin<<<4, 64, 0, stream>>>(evraw, ttraw, dout);
}